// Round 5
// baseline (537.484 us; speedup 1.0000x reference)
//
#include <hip/hip_runtime.h>
#include <math.h>

#define DIM 128
#define NEG 0.2f
#define EPS 1e-5f
#define LOG2E 1.4426950408889634f

#if __has_builtin(__builtin_amdgcn_exp2f)
#define EXP2(x) __builtin_amdgcn_exp2f(x)
#else
#define EXP2(x) exp2f(x)
#endif

static __device__ __forceinline__ float leaky(float a) { return a > 0.f ? a : NEG * a; }
static __device__ __forceinline__ unsigned short f2bf(float f) {
    unsigned int u = __float_as_uint(f);
    unsigned int r = (u + 0x7fffu + ((u >> 16) & 1u)) >> 16;  // RNE
    return (unsigned short)r;
}

// ---------------- K1: h = x@W, bf16x2-packed dword out, + a_src/a_dst dots --
// Lane l owns adjacent channels {2l, 2l+1} (both in head l>>4).
// att dots pre-scaled by log2(e) so k_agg can use raw v_exp_f32 (exp2).
__global__ __launch_bounds__(512, 4) void k_gemm(const float* __restrict__ x,
                                                 const float* __restrict__ W,
                                                 const float* __restrict__ att_s,
                                                 const float* __restrict__ att_d,
                                                 unsigned int* __restrict__ hpk,
                                                 float* __restrict__ asrc,
                                                 float* __restrict__ adst, int n) {
    __shared__ float2 Ws[DIM][64];   // Ws[k][c] = {W[k][2c], W[k][2c+1]}
    __shared__ float4 xs[8][4][32];  // per-wave 4 staged rows of x
    for (int idx = threadIdx.x; idx < DIM * 64; idx += 512) {
        int k = idx >> 6, c = idx & 63;
        Ws[k][c] = *(const float2*)(W + k * DIM + 2 * c);
    }
    const int w = threadIdx.x >> 6;
    const int lane = threadIdx.x & 63;
    const float as0 = att_s[2 * lane] * LOG2E, as1 = att_s[2 * lane + 1] * LOG2E;
    const float ad0 = att_d[2 * lane] * LOG2E, ad1 = att_d[2 * lane + 1] * LOG2E;
    const int r0 = blockIdx.x * 32 + w * 4;
    {   // coalesced stage: wave reads 2x 1KB contiguous (rows r0..r0+3)
        int f0 = lane, f1 = 64 + lane;
        int ra = min(r0 + (f0 >> 5), n - 1);
        int rc = min(r0 + (f1 >> 5), n - 1);
        xs[w][f0 >> 5][f0 & 31] = ((const float4*)x)[(size_t)ra * 32 + (f0 & 31)];
        xs[w][f1 >> 5][f1 & 31] = ((const float4*)x)[(size_t)rc * 32 + (f1 & 31)];
    }
    __syncthreads();
    float a00 = 0.f, a01 = 0.f, a10 = 0.f, a11 = 0.f;
    float a20 = 0.f, a21 = 0.f, a30 = 0.f, a31 = 0.f;
    for (int k4 = 0; k4 < 32; ++k4) {
        float4 xv0 = xs[w][0][k4];
        float4 xv1 = xs[w][1][k4];
        float4 xv2 = xs[w][2][k4];
        float4 xv3 = xs[w][3][k4];
#pragma unroll
        for (int kk = 0; kk < 4; ++kk) {
            float2 wv = Ws[k4 * 4 + kk][lane];
            float x0 = ((const float*)&xv0)[kk];
            float x1 = ((const float*)&xv1)[kk];
            float x2 = ((const float*)&xv2)[kk];
            float x3 = ((const float*)&xv3)[kk];
            a00 = fmaf(x0, wv.x, a00); a01 = fmaf(x0, wv.y, a01);
            a10 = fmaf(x1, wv.x, a10); a11 = fmaf(x1, wv.y, a11);
            a20 = fmaf(x2, wv.x, a20); a21 = fmaf(x2, wv.y, a21);
            a30 = fmaf(x3, wv.x, a30); a31 = fmaf(x3, wv.y, a31);
        }
    }
    float accs0[4] = {a00, a10, a20, a30};  // channel 2l
    float accs1[4] = {a01, a11, a21, a31};  // channel 2l+1
#pragma unroll
    for (int rr = 0; rr < 4; ++rr) {
        int r = r0 + rr;
        if (r >= n) break;  // wave-uniform
        float h0 = accs0[rr], h1 = accs1[rr];
        float p = h0 * as0 + h1 * as1;   // per-head partial dot (log2e-scaled)
        float q = h0 * ad0 + h1 * ad1;
#pragma unroll
        for (int m = 1; m < 16; m <<= 1) {  // reduce within 16-lane head group
            p += __shfl_xor(p, m);
            q += __shfl_xor(q, m);
        }
        hpk[(size_t)r * 64 + lane] = (unsigned int)f2bf(h0) | ((unsigned int)f2bf(h1) << 16);
        if ((lane & 15) == 0) {
            int hd = lane >> 4;
            asrc[r * 4 + hd] = p;
            adst[r * 4 + hd] = q;
        }
    }
}

// ---------------- K2: init deg=1 (self loop) and zero BN stats ----------------
__global__ void k_init(int* __restrict__ deg, float* __restrict__ stats, int n) {
    int t = blockIdx.x * blockDim.x + threadIdx.x;
    if (t < n) deg[t] = 1;
    if (t < 256) stats[t] = 0.f;
}

// ---------------- K3: histogram of dst ----------------
__global__ void k_hist(const int* __restrict__ dst, int* __restrict__ deg, int E) {
    int t = blockIdx.x * blockDim.x + threadIdx.x;
    if (t < E) atomicAdd(&deg[dst[t]], 1);
}

// ---------------- K4abc: device-wide exclusive scan of deg (1024 elems/block) --
__global__ __launch_bounds__(256) void k_scan_part(const int* __restrict__ deg,
                                                   int* __restrict__ bsum, int n) {
    int idx = blockIdx.x * 1024 + threadIdx.x * 4;
    int4 v = {0, 0, 0, 0};
    if (idx + 3 < n) v = *(const int4*)(deg + idx);
    else {
        if (idx + 0 < n) v.x = deg[idx + 0];
        if (idx + 1 < n) v.y = deg[idx + 1];
        if (idx + 2 < n) v.z = deg[idx + 2];
    }
    int s = v.x + v.y + v.z + v.w;
#pragma unroll
    for (int m = 1; m < 64; m <<= 1) s += __shfl_xor(s, m);
    __shared__ int ws[4];
    if ((threadIdx.x & 63) == 0) ws[threadIdx.x >> 6] = s;
    __syncthreads();
    if (threadIdx.x == 0) bsum[blockIdx.x] = ws[0] + ws[1] + ws[2] + ws[3];
}

__global__ __launch_bounds__(256) void k_scan_tops(int* __restrict__ bsum, int B) {
    __shared__ int lds[256];
    int t = threadIdx.x;
    int v = (t < B) ? bsum[t] : 0;
    lds[t] = v;
    __syncthreads();
    int acc = v;
    for (int ofs = 1; ofs < 256; ofs <<= 1) {
        int u = (t >= ofs) ? lds[t - ofs] : 0;
        __syncthreads();
        acc += u;
        lds[t] = acc;
        __syncthreads();
    }
    if (t < B) bsum[t] = acc - v;  // exclusive block offsets (in place)
}

__global__ __launch_bounds__(256) void k_scan_add(const int* __restrict__ deg,
                                                  const int* __restrict__ bsum,
                                                  int* __restrict__ row_start,
                                                  int* __restrict__ cursor, int n, int total) {
    int t = threadIdx.x;
    int idx = blockIdx.x * 1024 + t * 4;
    int4 v = {0, 0, 0, 0};
    if (idx + 3 < n) v = *(const int4*)(deg + idx);
    else {
        if (idx + 0 < n) v.x = deg[idx + 0];
        if (idx + 1 < n) v.y = deg[idx + 1];
        if (idx + 2 < n) v.z = deg[idx + 2];
    }
    int s = v.x + v.y + v.z + v.w;
    __shared__ int lds[256];
    lds[t] = s;
    __syncthreads();
    int acc = s;
    for (int ofs = 1; ofs < 256; ofs <<= 1) {
        int u = (t >= ofs) ? lds[t - ofs] : 0;
        __syncthreads();
        acc += u;
        lds[t] = acc;
        __syncthreads();
    }
    int excl = bsum[blockIdx.x] + acc - s;
    int4 rs;
    rs.x = excl;
    rs.y = rs.x + v.x;
    rs.z = rs.y + v.y;
    rs.w = rs.z + v.z;
    if (idx + 3 < n) {
        *(int4*)(row_start + idx) = rs;
        *(int4*)(cursor + idx) = rs;
    } else {
        if (idx + 0 < n) { row_start[idx + 0] = rs.x; cursor[idx + 0] = rs.x; }
        if (idx + 1 < n) { row_start[idx + 1] = rs.y; cursor[idx + 1] = rs.y; }
        if (idx + 2 < n) { row_start[idx + 2] = rs.z; cursor[idx + 2] = rs.z; }
    }
    if (blockIdx.x == 0 && t == 0) row_start[n] = total;
}

// ---------------- K5: scatter edges (and self loops) into CSR ----------------
__global__ void k_scatter(const int* __restrict__ src, const int* __restrict__ dst,
                          int* __restrict__ cursor, int* __restrict__ csr, int E, int n) {
    int t = blockIdx.x * blockDim.x + threadIdx.x;
    if (t < E) {
        int d = dst[t];
        int slot = atomicAdd(&cursor[d], 1);
        csr[slot] = src[t];
    } else if (t < E + n) {
        int i = t - E;
        int slot = atomicAdd(&cursor[i], 1);
        csr[slot] = i;
    }
}

// ---------------- K6: per-dst-node two-pass softmax aggregation + residual
//                      + bias + BN partial stats. One wave per node.
//                      Lane l: channels {2l,2l+1}, head l>>4, ONE exp/edge. ----
__global__ __launch_bounds__(256) void k_agg(const unsigned int* __restrict__ hw,
                                             const float* __restrict__ asrc,
                                             const float* __restrict__ adst,
                                             const int* __restrict__ row_start,
                                             const int* __restrict__ csr,
                                             const float* __restrict__ prev,
                                             const float* __restrict__ bias,
                                             float* __restrict__ ypre,
                                             float* __restrict__ stats, int n) {
    const int lane = threadIdx.x & 63;
    const int hd = lane >> 4;  // head for channels {2l, 2l+1}
    int wave = blockIdx.x * 4 + (threadIdx.x >> 6);
    int nw = gridDim.x * 4;
    const float2 bb = *(const float2*)(bias + 2 * lane);
    float bsum0 = 0.f, bsq0 = 0.f, bsum1 = 0.f, bsq1 = 0.f;
    for (int i0 = wave; i0 < n; i0 += nw) {
        int i = __builtin_amdgcn_readfirstlane(i0);
        int e0 = row_start[i], e1 = row_start[i + 1];
        const float adx = adst[i * 4 + hd];
        // pass 1: exact max (log2e-scaled domain)
        float m = -1e30f;
        for (int e = e0; e < e1; ++e) {
            int j = csr[e];
            m = fmaxf(m, leaky(asrc[j * 4 + hd] + adx));
        }
        // pass 2: p = 2^(al - m); accumulate s, p*h
        float s = 0.f, acc0 = 0.f, acc1 = 0.f;
        for (int e = e0; e < e1; ++e) {
            int j = csr[e];
            float al = leaky(asrc[j * 4 + hd] + adx);
            float p = EXP2(al - m);
            unsigned int hp = hw[(size_t)j * 64 + lane];
            float h0 = __uint_as_float(hp << 16);
            float h1 = __uint_as_float(hp & 0xffff0000u);
            s += p;
            acc0 = fmaf(p, h0, acc0);
            acc1 = fmaf(p, h1, acc1);
        }
        float rs = 1.0f / s;
        const float2 pv = *(const float2*)(prev + (size_t)i * DIM + 2 * lane);
        float o0 = fmaf(acc0, rs, bb.x + pv.x);
        float o1 = fmaf(acc1, rs, bb.y + pv.y);
        *(float2*)(ypre + (size_t)i * DIM + 2 * lane) = make_float2(o0, o1);
        bsum0 += o0; bsq0 = fmaf(o0, o0, bsq0);
        bsum1 += o1; bsq1 = fmaf(o1, o1, bsq1);
    }
    __shared__ float red[4][256];
    red[0][threadIdx.x] = bsum0;
    red[1][threadIdx.x] = bsq0;
    red[2][threadIdx.x] = bsum1;
    red[3][threadIdx.x] = bsq1;
    __syncthreads();
    if (threadIdx.x < 64) {
        int t = threadIdx.x;
        float v0 = red[0][t] + red[0][t + 64] + red[0][t + 128] + red[0][t + 192];
        float v1 = red[1][t] + red[1][t + 64] + red[1][t + 128] + red[1][t + 192];
        float v2 = red[2][t] + red[2][t + 64] + red[2][t + 128] + red[2][t + 192];
        float v3 = red[3][t] + red[3][t + 64] + red[3][t + 128] + red[3][t + 192];
        atomicAdd(&stats[2 * t], v0);          // sum, channel 2t
        atomicAdd(&stats[2 * t + 1], v2);      // sum, channel 2t+1
        atomicAdd(&stats[128 + 2 * t], v1);    // sumsq, channel 2t
        atomicAdd(&stats[128 + 2 * t + 1], v3);// sumsq, channel 2t+1
    }
}

// ---------------- K7: finalize BN scale/shift ----------------
__global__ void k_bnfin(const float* __restrict__ stats, const float* __restrict__ gamma,
                        const float* __restrict__ beta, float* __restrict__ AB, int n) {
    int c = threadIdx.x;  // 128 threads
    float fn = (float)n;
    float mean = stats[c] / fn;
    float var = stats[128 + c] / fn - mean * mean;
    float a = gamma[c] * rsqrtf(var + EPS);
    AB[c] = a;
    AB[128 + c] = beta[c] - mean * a;
}

// ---------------- K8: y = relu(y*A + B), in place, float4 ----------------
__global__ __launch_bounds__(256) void k_final(float* __restrict__ y,
                                               const float* __restrict__ AB, int total4) {
    int t0 = blockIdx.x * blockDim.x + threadIdx.x;
    int stride = gridDim.x * blockDim.x;
    for (int t = t0; t < total4; t += stride) {
        float4 v = ((float4*)y)[t];
        int c0 = (t * 4) & 127;
        v.x = fmaf(v.x, AB[c0 + 0], AB[128 + c0 + 0]);
        v.y = fmaf(v.y, AB[c0 + 1], AB[128 + c0 + 1]);
        v.z = fmaf(v.z, AB[c0 + 2], AB[128 + c0 + 2]);
        v.w = fmaf(v.w, AB[c0 + 3], AB[128 + c0 + 3]);
        v.x = v.x > 0.f ? v.x : 0.f;
        v.y = v.y > 0.f ? v.y : 0.f;
        v.z = v.z > 0.f ? v.z : 0.f;
        v.w = v.w > 0.f ? v.w : 0.f;
        ((float4*)y)[t] = v;
    }
}

extern "C" void kernel_launch(void* const* d_in, const int* in_sizes, int n_in,
                              void* d_out, int out_size, void* d_ws, size_t ws_size,
                              hipStream_t stream) {
    const float* prev  = (const float*)d_in[0];
    const float* x     = (const float*)d_in[1];
    const int*   ei    = (const int*)d_in[2];
    const float* W     = (const float*)d_in[3];
    const float* att_s = (const float*)d_in[4];
    const float* att_d = (const float*)d_in[5];
    const float* bias  = (const float*)d_in[6];
    const float* gamma = (const float*)d_in[7];
    const float* beta  = (const float*)d_in[8];
    const int n = in_sizes[0] / DIM;
    const int E = in_sizes[2] / 2;
    const int* src = ei;
    const int* dst = ei + E;

    char* p = (char*)d_ws;
    auto alloc = [&](size_t bytes) {
        void* q = (void*)p;
        p += (bytes + 255) & ~(size_t)255;
        return q;
    };
    unsigned int* hpk = (unsigned int*)alloc((size_t)n * 64 * 4);
    float* asrc      = (float*)alloc((size_t)n * 4 * 4);
    float* adst      = (float*)alloc((size_t)n * 4 * 4);
    int*   deg       = (int*)alloc((size_t)(n + 1) * 4);
    int*   row_start = (int*)alloc((size_t)(n + 1) * 4);
    int*   cursor    = (int*)alloc((size_t)(n + 1) * 4);
    int*   csr       = (int*)alloc((size_t)(E + n) * 4);
    int*   bsum      = (int*)alloc(1024 * 4);
    float* stats     = (float*)alloc(256 * 4);
    float* AB        = (float*)alloc(256 * 4);
    float* yout      = (float*)d_out;

    int B = (n + 1023) / 1024;  // scan blocks (<=256 for n<=262144)
    k_init<<<dim3((n + 255) / 256), dim3(256), 0, stream>>>(deg, stats, n);
    k_gemm<<<dim3((n + 31) / 32), dim3(512), 0, stream>>>(x, W, att_s, att_d, hpk, asrc, adst, n);
    k_hist<<<dim3((E + 255) / 256), dim3(256), 0, stream>>>(dst, deg, E);
    k_scan_part<<<dim3(B), dim3(256), 0, stream>>>(deg, bsum, n);
    k_scan_tops<<<dim3(1), dim3(256), 0, stream>>>(bsum, B);
    k_scan_add<<<dim3(B), dim3(256), 0, stream>>>(deg, bsum, row_start, cursor, n, E + n);
    k_scatter<<<dim3((E + n + 255) / 256), dim3(256), 0, stream>>>(src, dst, cursor, csr, E, n);
    k_agg<<<dim3(2048), dim3(256), 0, stream>>>(hpk, asrc, adst, row_start, csr, prev, bias, yout, stats, n);
    k_bnfin<<<dim3(1), dim3(128), 0, stream>>>(stats, gamma, beta, AB, n);
    int total4 = n * DIM / 4;
    k_final<<<dim3(2048), dim3(256), 0, stream>>>(yout, AB, total4);
}

// Round 6
// 497.863 us; speedup vs baseline: 1.0796x; 1.0796x over previous
//
#include <hip/hip_runtime.h>
#include <math.h>

#define DIM 128
#define NEG 0.2f
#define EPS 1e-5f
#define LOG2E 1.4426950408889634f

#if __has_builtin(__builtin_amdgcn_exp2f)
#define EXP2(x) __builtin_amdgcn_exp2f(x)
#else
#define EXP2(x) exp2f(x)
#endif

static __device__ __forceinline__ float leaky(float a) { return a > 0.f ? a : NEG * a; }
static __device__ __forceinline__ unsigned short f2bf(float f) {
    unsigned int u = __float_as_uint(f);
    unsigned int r = (u + 0x7fffu + ((u >> 16) & 1u)) >> 16;  // RNE
    return (unsigned short)r;
}

// ---------------- K1: h = x@W, bf16x2-packed dword out, + a_src/a_dst dots --
// Lane l owns adjacent channels {2l, 2l+1} (both in head l>>4).
// att dots pre-scaled by log2(e) so k_agg can use raw v_exp_f32 (exp2).
__global__ __launch_bounds__(512, 4) void k_gemm(const float* __restrict__ x,
                                                 const float* __restrict__ W,
                                                 const float* __restrict__ att_s,
                                                 const float* __restrict__ att_d,
                                                 unsigned int* __restrict__ hpk,
                                                 float* __restrict__ asrc,
                                                 float* __restrict__ adst, int n) {
    __shared__ float2 Ws[DIM][64];   // Ws[k][c] = {W[k][2c], W[k][2c+1]}
    __shared__ float4 xs[8][4][32];  // per-wave 4 staged rows of x
    for (int idx = threadIdx.x; idx < DIM * 64; idx += 512) {
        int k = idx >> 6, c = idx & 63;
        Ws[k][c] = *(const float2*)(W + k * DIM + 2 * c);
    }
    const int w = threadIdx.x >> 6;
    const int lane = threadIdx.x & 63;
    const float as0 = att_s[2 * lane] * LOG2E, as1 = att_s[2 * lane + 1] * LOG2E;
    const float ad0 = att_d[2 * lane] * LOG2E, ad1 = att_d[2 * lane + 1] * LOG2E;
    const int r0 = blockIdx.x * 32 + w * 4;
    {   // coalesced stage: wave reads 2x 1KB contiguous (rows r0..r0+3)
        int f0 = lane, f1 = 64 + lane;
        int ra = min(r0 + (f0 >> 5), n - 1);
        int rc = min(r0 + (f1 >> 5), n - 1);
        xs[w][f0 >> 5][f0 & 31] = ((const float4*)x)[(size_t)ra * 32 + (f0 & 31)];
        xs[w][f1 >> 5][f1 & 31] = ((const float4*)x)[(size_t)rc * 32 + (f1 & 31)];
    }
    __syncthreads();
    float a00 = 0.f, a01 = 0.f, a10 = 0.f, a11 = 0.f;
    float a20 = 0.f, a21 = 0.f, a30 = 0.f, a31 = 0.f;
    for (int k4 = 0; k4 < 32; ++k4) {
        float4 xv0 = xs[w][0][k4];
        float4 xv1 = xs[w][1][k4];
        float4 xv2 = xs[w][2][k4];
        float4 xv3 = xs[w][3][k4];
#pragma unroll
        for (int kk = 0; kk < 4; ++kk) {
            float2 wv = Ws[k4 * 4 + kk][lane];
            float x0 = ((const float*)&xv0)[kk];
            float x1 = ((const float*)&xv1)[kk];
            float x2 = ((const float*)&xv2)[kk];
            float x3 = ((const float*)&xv3)[kk];
            a00 = fmaf(x0, wv.x, a00); a01 = fmaf(x0, wv.y, a01);
            a10 = fmaf(x1, wv.x, a10); a11 = fmaf(x1, wv.y, a11);
            a20 = fmaf(x2, wv.x, a20); a21 = fmaf(x2, wv.y, a21);
            a30 = fmaf(x3, wv.x, a30); a31 = fmaf(x3, wv.y, a31);
        }
    }
    float accs0[4] = {a00, a10, a20, a30};  // channel 2l
    float accs1[4] = {a01, a11, a21, a31};  // channel 2l+1
#pragma unroll
    for (int rr = 0; rr < 4; ++rr) {
        int r = r0 + rr;
        if (r >= n) break;  // wave-uniform
        float h0 = accs0[rr], h1 = accs1[rr];
        float p = h0 * as0 + h1 * as1;   // per-head partial dot (log2e-scaled)
        float q = h0 * ad0 + h1 * ad1;
#pragma unroll
        for (int m = 1; m < 16; m <<= 1) {  // reduce within 16-lane head group
            p += __shfl_xor(p, m);
            q += __shfl_xor(q, m);
        }
        hpk[(size_t)r * 64 + lane] = (unsigned int)f2bf(h0) | ((unsigned int)f2bf(h1) << 16);
        if ((lane & 15) == 0) {
            int hd = lane >> 4;
            asrc[r * 4 + hd] = p;
            adst[r * 4 + hd] = q;
        }
    }
}

// ---------------- K2: init deg=1 (self loop) and zero BN stats ----------------
__global__ void k_init(int* __restrict__ deg, float* __restrict__ stats, int n) {
    int t = blockIdx.x * blockDim.x + threadIdx.x;
    if (t < n) deg[t] = 1;
    if (t < 256) stats[t] = 0.f;
}

// ---------------- K3: histogram of dst ----------------
__global__ void k_hist(const int* __restrict__ dst, int* __restrict__ deg, int E) {
    int t = blockIdx.x * blockDim.x + threadIdx.x;
    if (t < E) atomicAdd(&deg[dst[t]], 1);
}

// ---------------- K4abc: device-wide exclusive scan of deg (1024 elems/block) --
__global__ __launch_bounds__(256) void k_scan_part(const int* __restrict__ deg,
                                                   int* __restrict__ bsum, int n) {
    int idx = blockIdx.x * 1024 + threadIdx.x * 4;
    int4 v = {0, 0, 0, 0};
    if (idx + 3 < n) v = *(const int4*)(deg + idx);
    else {
        if (idx + 0 < n) v.x = deg[idx + 0];
        if (idx + 1 < n) v.y = deg[idx + 1];
        if (idx + 2 < n) v.z = deg[idx + 2];
    }
    int s = v.x + v.y + v.z + v.w;
#pragma unroll
    for (int m = 1; m < 64; m <<= 1) s += __shfl_xor(s, m);
    __shared__ int ws[4];
    if ((threadIdx.x & 63) == 0) ws[threadIdx.x >> 6] = s;
    __syncthreads();
    if (threadIdx.x == 0) bsum[blockIdx.x] = ws[0] + ws[1] + ws[2] + ws[3];
}

__global__ __launch_bounds__(256) void k_scan_tops(int* __restrict__ bsum, int B) {
    __shared__ int lds[256];
    int t = threadIdx.x;
    int v = (t < B) ? bsum[t] : 0;
    lds[t] = v;
    __syncthreads();
    int acc = v;
    for (int ofs = 1; ofs < 256; ofs <<= 1) {
        int u = (t >= ofs) ? lds[t - ofs] : 0;
        __syncthreads();
        acc += u;
        lds[t] = acc;
        __syncthreads();
    }
    if (t < B) bsum[t] = acc - v;  // exclusive block offsets (in place)
}

__global__ __launch_bounds__(256) void k_scan_add(const int* __restrict__ deg,
                                                  const int* __restrict__ bsum,
                                                  int* __restrict__ row_start,
                                                  int* __restrict__ cursor, int n, int total) {
    int t = threadIdx.x;
    int idx = blockIdx.x * 1024 + t * 4;
    int4 v = {0, 0, 0, 0};
    if (idx + 3 < n) v = *(const int4*)(deg + idx);
    else {
        if (idx + 0 < n) v.x = deg[idx + 0];
        if (idx + 1 < n) v.y = deg[idx + 1];
        if (idx + 2 < n) v.z = deg[idx + 2];
    }
    int s = v.x + v.y + v.z + v.w;
    __shared__ int lds[256];
    lds[t] = s;
    __syncthreads();
    int acc = s;
    for (int ofs = 1; ofs < 256; ofs <<= 1) {
        int u = (t >= ofs) ? lds[t - ofs] : 0;
        __syncthreads();
        acc += u;
        lds[t] = acc;
        __syncthreads();
    }
    int excl = bsum[blockIdx.x] + acc - s;
    int4 rs;
    rs.x = excl;
    rs.y = rs.x + v.x;
    rs.z = rs.y + v.y;
    rs.w = rs.z + v.z;
    if (idx + 3 < n) {
        *(int4*)(row_start + idx) = rs;
        *(int4*)(cursor + idx) = rs;
    } else {
        if (idx + 0 < n) { row_start[idx + 0] = rs.x; cursor[idx + 0] = rs.x; }
        if (idx + 1 < n) { row_start[idx + 1] = rs.y; cursor[idx + 1] = rs.y; }
        if (idx + 2 < n) { row_start[idx + 2] = rs.z; cursor[idx + 2] = rs.z; }
    }
    if (blockIdx.x == 0 && t == 0) row_start[n] = total;
}

// ---------------- K5: scatter edges (and self loops) into CSR ----------------
__global__ void k_scatter(const int* __restrict__ src, const int* __restrict__ dst,
                          int* __restrict__ cursor, int* __restrict__ csr, int E, int n) {
    int t = blockIdx.x * blockDim.x + threadIdx.x;
    if (t < E) {
        int d = dst[t];
        int slot = atomicAdd(&cursor[d], 1);
        csr[slot] = src[t];
    } else if (t < E + n) {
        int i = t - E;
        int slot = atomicAdd(&cursor[i], 1);
        csr[slot] = i;
    }
}

// ---------------- K6: per-dst-node single-pass max-free softmax aggregation
//                      + residual + bias + BN partial stats. One wave per node.
//                      Lane l: channels {2l,2l+1}, head l>>4, ONE exp/edge.
//                      Softmax shift-invariance => no max pass needed (logits
//                      bounded ~|22| in log2 domain; fp32 range is ample). ----
__global__ __launch_bounds__(256) void k_agg(const unsigned int* __restrict__ hw,
                                             const float* __restrict__ asrc,
                                             const float* __restrict__ adst,
                                             const int* __restrict__ row_start,
                                             const int* __restrict__ csr,
                                             const float* __restrict__ prev,
                                             const float* __restrict__ bias,
                                             float* __restrict__ ypre,
                                             float* __restrict__ stats, int n) {
    const int lane = threadIdx.x & 63;
    const int hd = lane >> 4;  // head for channels {2l, 2l+1}
    int wave = blockIdx.x * 4 + (threadIdx.x >> 6);
    int nw = gridDim.x * 4;
    const float2 bb = *(const float2*)(bias + 2 * lane);
    float bsum0 = 0.f, bsq0 = 0.f, bsum1 = 0.f, bsq1 = 0.f;
    for (int i0 = wave; i0 < n; i0 += nw) {
        int i = __builtin_amdgcn_readfirstlane(i0);
        int e0 = row_start[i], e1 = row_start[i + 1];
        const float adx = adst[i * 4 + hd];
        float s = 0.f, acc0 = 0.f, acc1 = 0.f;
        for (int e = e0; e < e1; ++e) {
            int j = csr[e];
            float al = leaky(asrc[j * 4 + hd] + adx);
            float p = EXP2(al);  // unnormalized; shift-invariant softmax
            unsigned int hp = hw[(size_t)j * 64 + lane];
            float h0 = __uint_as_float(hp << 16);
            float h1 = __uint_as_float(hp & 0xffff0000u);
            s += p;
            acc0 = fmaf(p, h0, acc0);
            acc1 = fmaf(p, h1, acc1);
        }
        float rs = 1.0f / s;
        const float2 pv = *(const float2*)(prev + (size_t)i * DIM + 2 * lane);
        float o0 = fmaf(acc0, rs, bb.x + pv.x);
        float o1 = fmaf(acc1, rs, bb.y + pv.y);
        *(float2*)(ypre + (size_t)i * DIM + 2 * lane) = make_float2(o0, o1);
        bsum0 += o0; bsq0 = fmaf(o0, o0, bsq0);
        bsum1 += o1; bsq1 = fmaf(o1, o1, bsq1);
    }
    __shared__ float red[4][256];
    red[0][threadIdx.x] = bsum0;
    red[1][threadIdx.x] = bsq0;
    red[2][threadIdx.x] = bsum1;
    red[3][threadIdx.x] = bsq1;
    __syncthreads();
    if (threadIdx.x < 64) {
        int t = threadIdx.x;
        float v0 = red[0][t] + red[0][t + 64] + red[0][t + 128] + red[0][t + 192];
        float v1 = red[1][t] + red[1][t + 64] + red[1][t + 128] + red[1][t + 192];
        float v2 = red[2][t] + red[2][t + 64] + red[2][t + 128] + red[2][t + 192];
        float v3 = red[3][t] + red[3][t + 64] + red[3][t + 128] + red[3][t + 192];
        atomicAdd(&stats[2 * t], v0);          // sum, channel 2t
        atomicAdd(&stats[2 * t + 1], v2);      // sum, channel 2t+1
        atomicAdd(&stats[128 + 2 * t], v1);    // sumsq, channel 2t
        atomicAdd(&stats[128 + 2 * t + 1], v3);// sumsq, channel 2t+1
    }
}

// ---------------- K7: finalize BN scale/shift ----------------
__global__ void k_bnfin(const float* __restrict__ stats, const float* __restrict__ gamma,
                        const float* __restrict__ beta, float* __restrict__ AB, int n) {
    int c = threadIdx.x;  // 128 threads
    float fn = (float)n;
    float mean = stats[c] / fn;
    float var = stats[128 + c] / fn - mean * mean;
    float a = gamma[c] * rsqrtf(var + EPS);
    AB[c] = a;
    AB[128 + c] = beta[c] - mean * a;
}

// ---------------- K8: y = relu(y*A + B), in place, float4 ----------------
__global__ __launch_bounds__(256) void k_final(float* __restrict__ y,
                                               const float* __restrict__ AB, int total4) {
    int t0 = blockIdx.x * blockDim.x + threadIdx.x;
    int stride = gridDim.x * blockDim.x;
    for (int t = t0; t < total4; t += stride) {
        float4 v = ((float4*)y)[t];
        int c0 = (t * 4) & 127;
        v.x = fmaf(v.x, AB[c0 + 0], AB[128 + c0 + 0]);
        v.y = fmaf(v.y, AB[c0 + 1], AB[128 + c0 + 1]);
        v.z = fmaf(v.z, AB[c0 + 2], AB[128 + c0 + 2]);
        v.w = fmaf(v.w, AB[c0 + 3], AB[128 + c0 + 3]);
        v.x = v.x > 0.f ? v.x : 0.f;
        v.y = v.y > 0.f ? v.y : 0.f;
        v.z = v.z > 0.f ? v.z : 0.f;
        v.w = v.w > 0.f ? v.w : 0.f;
        ((float4*)y)[t] = v;
    }
}

extern "C" void kernel_launch(void* const* d_in, const int* in_sizes, int n_in,
                              void* d_out, int out_size, void* d_ws, size_t ws_size,
                              hipStream_t stream) {
    const float* prev  = (const float*)d_in[0];
    const float* x     = (const float*)d_in[1];
    const int*   ei    = (const int*)d_in[2];
    const float* W     = (const float*)d_in[3];
    const float* att_s = (const float*)d_in[4];
    const float* att_d = (const float*)d_in[5];
    const float* bias  = (const float*)d_in[6];
    const float* gamma = (const float*)d_in[7];
    const float* beta  = (const float*)d_in[8];
    const int n = in_sizes[0] / DIM;
    const int E = in_sizes[2] / 2;
    const int* src = ei;
    const int* dst = ei + E;

    char* p = (char*)d_ws;
    auto alloc = [&](size_t bytes) {
        void* q = (void*)p;
        p += (bytes + 255) & ~(size_t)255;
        return q;
    };
    unsigned int* hpk = (unsigned int*)alloc((size_t)n * 64 * 4);
    float* asrc      = (float*)alloc((size_t)n * 4 * 4);
    float* adst      = (float*)alloc((size_t)n * 4 * 4);
    int*   deg       = (int*)alloc((size_t)(n + 1) * 4);
    int*   row_start = (int*)alloc((size_t)(n + 1) * 4);
    int*   cursor    = (int*)alloc((size_t)(n + 1) * 4);
    int*   csr       = (int*)alloc((size_t)(E + n) * 4);
    int*   bsum      = (int*)alloc(1024 * 4);
    float* stats     = (float*)alloc(256 * 4);
    float* AB        = (float*)alloc(256 * 4);
    float* yout      = (float*)d_out;

    int B = (n + 1023) / 1024;  // scan blocks (<=256 for n<=262144)
    k_init<<<dim3((n + 255) / 256), dim3(256), 0, stream>>>(deg, stats, n);
    k_gemm<<<dim3((n + 31) / 32), dim3(512), 0, stream>>>(x, W, att_s, att_d, hpk, asrc, adst, n);
    k_hist<<<dim3((E + 255) / 256), dim3(256), 0, stream>>>(dst, deg, E);
    k_scan_part<<<dim3(B), dim3(256), 0, stream>>>(deg, bsum, n);
    k_scan_tops<<<dim3(1), dim3(256), 0, stream>>>(bsum, B);
    k_scan_add<<<dim3(B), dim3(256), 0, stream>>>(deg, bsum, row_start, cursor, n, E + n);
    k_scatter<<<dim3((E + n + 255) / 256), dim3(256), 0, stream>>>(src, dst, cursor, csr, E, n);
    k_agg<<<dim3(2048), dim3(256), 0, stream>>>(hpk, asrc, adst, row_start, csr, prev, bias, yout, stats, n);
    k_bnfin<<<dim3(1), dim3(128), 0, stream>>>(stats, gamma, beta, AB, n);
    int total4 = n * DIM / 4;
    k_final<<<dim3(2048), dim3(256), 0, stream>>>(yout, AB, total4);
}

// Round 7
// 484.703 us; speedup vs baseline: 1.1089x; 1.0271x over previous
//
#include <hip/hip_runtime.h>
#include <math.h>

#define DIM 128
#define NEG 0.2f
#define EPS 1e-5f
#define LOG2E 1.4426950408889634f

#if __has_builtin(__builtin_amdgcn_exp2f)
#define EXP2(x) __builtin_amdgcn_exp2f(x)
#else
#define EXP2(x) exp2f(x)
#endif

static __device__ __forceinline__ float leaky(float a) { return a > 0.f ? a : NEG * a; }
static __device__ __forceinline__ unsigned short f2bf(float f) {
    unsigned int u = __float_as_uint(f);
    unsigned int r = (u + 0x7fffu + ((u >> 16) & 1u)) >> 16;  // RNE
    return (unsigned short)r;
}

// ---------------- K1: h = x@W, bf16x2-packed dword out, + a_src/a_dst dots --
// Lane l owns adjacent channels {2l, 2l+1} (both in head l>>4).
// att dots pre-scaled by log2(e) so k_agg can use raw v_exp_f32 (exp2).
__global__ __launch_bounds__(512, 4) void k_gemm(const float* __restrict__ x,
                                                 const float* __restrict__ W,
                                                 const float* __restrict__ att_s,
                                                 const float* __restrict__ att_d,
                                                 unsigned int* __restrict__ hpk,
                                                 float* __restrict__ asrc,
                                                 float* __restrict__ adst, int n) {
    __shared__ float2 Ws[DIM][64];   // Ws[k][c] = {W[k][2c], W[k][2c+1]}
    __shared__ float4 xs[8][4][32];  // per-wave 4 staged rows of x
    for (int idx = threadIdx.x; idx < DIM * 64; idx += 512) {
        int k = idx >> 6, c = idx & 63;
        Ws[k][c] = *(const float2*)(W + k * DIM + 2 * c);
    }
    const int w = threadIdx.x >> 6;
    const int lane = threadIdx.x & 63;
    const float as0 = att_s[2 * lane] * LOG2E, as1 = att_s[2 * lane + 1] * LOG2E;
    const float ad0 = att_d[2 * lane] * LOG2E, ad1 = att_d[2 * lane + 1] * LOG2E;
    const int r0 = blockIdx.x * 32 + w * 4;
    {   // coalesced stage: wave reads 2x 1KB contiguous (rows r0..r0+3)
        int f0 = lane, f1 = 64 + lane;
        int ra = min(r0 + (f0 >> 5), n - 1);
        int rc = min(r0 + (f1 >> 5), n - 1);
        xs[w][f0 >> 5][f0 & 31] = ((const float4*)x)[(size_t)ra * 32 + (f0 & 31)];
        xs[w][f1 >> 5][f1 & 31] = ((const float4*)x)[(size_t)rc * 32 + (f1 & 31)];
    }
    __syncthreads();
    float a00 = 0.f, a01 = 0.f, a10 = 0.f, a11 = 0.f;
    float a20 = 0.f, a21 = 0.f, a30 = 0.f, a31 = 0.f;
    for (int k4 = 0; k4 < 32; ++k4) {
        float4 xv0 = xs[w][0][k4];
        float4 xv1 = xs[w][1][k4];
        float4 xv2 = xs[w][2][k4];
        float4 xv3 = xs[w][3][k4];
#pragma unroll
        for (int kk = 0; kk < 4; ++kk) {
            float2 wv = Ws[k4 * 4 + kk][lane];
            float x0 = ((const float*)&xv0)[kk];
            float x1 = ((const float*)&xv1)[kk];
            float x2 = ((const float*)&xv2)[kk];
            float x3 = ((const float*)&xv3)[kk];
            a00 = fmaf(x0, wv.x, a00); a01 = fmaf(x0, wv.y, a01);
            a10 = fmaf(x1, wv.x, a10); a11 = fmaf(x1, wv.y, a11);
            a20 = fmaf(x2, wv.x, a20); a21 = fmaf(x2, wv.y, a21);
            a30 = fmaf(x3, wv.x, a30); a31 = fmaf(x3, wv.y, a31);
        }
    }
    float accs0[4] = {a00, a10, a20, a30};  // channel 2l
    float accs1[4] = {a01, a11, a21, a31};  // channel 2l+1
#pragma unroll
    for (int rr = 0; rr < 4; ++rr) {
        int r = r0 + rr;
        if (r >= n) break;  // wave-uniform
        float h0 = accs0[rr], h1 = accs1[rr];
        float p = h0 * as0 + h1 * as1;   // per-head partial dot (log2e-scaled)
        float q = h0 * ad0 + h1 * ad1;
#pragma unroll
        for (int m = 1; m < 16; m <<= 1) {  // reduce within 16-lane head group
            p += __shfl_xor(p, m);
            q += __shfl_xor(q, m);
        }
        hpk[(size_t)r * 64 + lane] = (unsigned int)f2bf(h0) | ((unsigned int)f2bf(h1) << 16);
        if ((lane & 15) == 0) {
            int hd = lane >> 4;
            asrc[r * 4 + hd] = p;
            adst[r * 4 + hd] = q;
        }
    }
}

// ---------------- K2: init deg=1 (self loop) and zero BN stats ----------------
__global__ void k_init(int* __restrict__ deg, float* __restrict__ stats, int n) {
    int t = blockIdx.x * blockDim.x + threadIdx.x;
    if (t < n) deg[t] = 1;
    if (t < 256) stats[t] = 0.f;
}

// ---------------- K3: histogram of dst ----------------
__global__ void k_hist(const int* __restrict__ dst, int* __restrict__ deg, int E) {
    int t = blockIdx.x * blockDim.x + threadIdx.x;
    if (t < E) atomicAdd(&deg[dst[t]], 1);
}

// ---------------- K4abc: device-wide exclusive scan of deg (1024 elems/block) --
__global__ __launch_bounds__(256) void k_scan_part(const int* __restrict__ deg,
                                                   int* __restrict__ bsum, int n) {
    int idx = blockIdx.x * 1024 + threadIdx.x * 4;
    int4 v = {0, 0, 0, 0};
    if (idx + 3 < n) v = *(const int4*)(deg + idx);
    else {
        if (idx + 0 < n) v.x = deg[idx + 0];
        if (idx + 1 < n) v.y = deg[idx + 1];
        if (idx + 2 < n) v.z = deg[idx + 2];
    }
    int s = v.x + v.y + v.z + v.w;
#pragma unroll
    for (int m = 1; m < 64; m <<= 1) s += __shfl_xor(s, m);
    __shared__ int ws[4];
    if ((threadIdx.x & 63) == 0) ws[threadIdx.x >> 6] = s;
    __syncthreads();
    if (threadIdx.x == 0) bsum[blockIdx.x] = ws[0] + ws[1] + ws[2] + ws[3];
}

__global__ __launch_bounds__(256) void k_scan_tops(int* __restrict__ bsum, int B) {
    __shared__ int lds[256];
    int t = threadIdx.x;
    int v = (t < B) ? bsum[t] : 0;
    lds[t] = v;
    __syncthreads();
    int acc = v;
    for (int ofs = 1; ofs < 256; ofs <<= 1) {
        int u = (t >= ofs) ? lds[t - ofs] : 0;
        __syncthreads();
        acc += u;
        lds[t] = acc;
        __syncthreads();
    }
    if (t < B) bsum[t] = acc - v;  // exclusive block offsets (in place)
}

__global__ __launch_bounds__(256) void k_scan_add(const int* __restrict__ deg,
                                                  const int* __restrict__ bsum,
                                                  int* __restrict__ row_start,
                                                  int* __restrict__ cursor, int n, int total) {
    int t = threadIdx.x;
    int idx = blockIdx.x * 1024 + t * 4;
    int4 v = {0, 0, 0, 0};
    if (idx + 3 < n) v = *(const int4*)(deg + idx);
    else {
        if (idx + 0 < n) v.x = deg[idx + 0];
        if (idx + 1 < n) v.y = deg[idx + 1];
        if (idx + 2 < n) v.z = deg[idx + 2];
    }
    int s = v.x + v.y + v.z + v.w;
    __shared__ int lds[256];
    lds[t] = s;
    __syncthreads();
    int acc = s;
    for (int ofs = 1; ofs < 256; ofs <<= 1) {
        int u = (t >= ofs) ? lds[t - ofs] : 0;
        __syncthreads();
        acc += u;
        lds[t] = acc;
        __syncthreads();
    }
    int excl = bsum[blockIdx.x] + acc - s;
    int4 rs;
    rs.x = excl;
    rs.y = rs.x + v.x;
    rs.z = rs.y + v.y;
    rs.w = rs.z + v.z;
    if (idx + 3 < n) {
        *(int4*)(row_start + idx) = rs;
        *(int4*)(cursor + idx) = rs;
    } else {
        if (idx + 0 < n) { row_start[idx + 0] = rs.x; cursor[idx + 0] = rs.x; }
        if (idx + 1 < n) { row_start[idx + 1] = rs.y; cursor[idx + 1] = rs.y; }
        if (idx + 2 < n) { row_start[idx + 2] = rs.z; cursor[idx + 2] = rs.z; }
    }
    if (blockIdx.x == 0 && t == 0) row_start[n] = total;
}

// ---------------- K5: scatter edges (and self loops) into CSR ----------------
__global__ void k_scatter(const int* __restrict__ src, const int* __restrict__ dst,
                          int* __restrict__ cursor, int* __restrict__ csr, int E, int n) {
    int t = blockIdx.x * blockDim.x + threadIdx.x;
    if (t < E) {
        int d = dst[t];
        int slot = atomicAdd(&cursor[d], 1);
        csr[slot] = src[t];
    } else if (t < E + n) {
        int i = t - E;
        int slot = atomicAdd(&cursor[i], 1);
        csr[slot] = i;
    }
}

// ---------------- K6: per-dst-node single-pass max-free softmax aggregation,
//                      4-edge unrolled for memory-level parallelism.
//                      One wave per node; lane l: channels {2l,2l+1}, head l>>4.
__global__ __launch_bounds__(256) void k_agg(const unsigned int* __restrict__ hw,
                                             const float* __restrict__ asrc,
                                             const float* __restrict__ adst,
                                             const int* __restrict__ row_start,
                                             const int* __restrict__ csr,
                                             const float* __restrict__ prev,
                                             const float* __restrict__ bias,
                                             float* __restrict__ ypre,
                                             float* __restrict__ stats, int n) {
    const int lane = threadIdx.x & 63;
    const int hd = lane >> 4;  // head for channels {2l, 2l+1}
    int wave = blockIdx.x * 4 + (threadIdx.x >> 6);
    int nw = gridDim.x * 4;
    const float2 bb = *(const float2*)(bias + 2 * lane);
    float bsum0 = 0.f, bsq0 = 0.f, bsum1 = 0.f, bsq1 = 0.f;
    for (int i0 = wave; i0 < n; i0 += nw) {
        int i = __builtin_amdgcn_readfirstlane(i0);
        int e0 = row_start[i], e1 = row_start[i + 1];
        const float adx = adst[i * 4 + hd];
        float s = 0.f, acc0 = 0.f, acc1 = 0.f;
        int e = e0;
        // 4-edge unrolled main loop: batch all gathers -> 4 outstanding loads
        for (; e + 4 <= e1; e += 4) {
            int j0 = csr[e + 0], j1 = csr[e + 1], j2 = csr[e + 2], j3 = csr[e + 3];
            float g0 = asrc[j0 * 4 + hd];
            float g1 = asrc[j1 * 4 + hd];
            float g2 = asrc[j2 * 4 + hd];
            float g3 = asrc[j3 * 4 + hd];
            unsigned int hp0 = hw[(size_t)j0 * 64 + lane];
            unsigned int hp1 = hw[(size_t)j1 * 64 + lane];
            unsigned int hp2 = hw[(size_t)j2 * 64 + lane];
            unsigned int hp3 = hw[(size_t)j3 * 64 + lane];
            float p0 = EXP2(leaky(g0 + adx));
            float p1 = EXP2(leaky(g1 + adx));
            float p2 = EXP2(leaky(g2 + adx));
            float p3 = EXP2(leaky(g3 + adx));
            s += (p0 + p1) + (p2 + p3);
            acc0 = fmaf(p0, __uint_as_float(hp0 << 16), acc0);
            acc1 = fmaf(p0, __uint_as_float(hp0 & 0xffff0000u), acc1);
            acc0 = fmaf(p1, __uint_as_float(hp1 << 16), acc0);
            acc1 = fmaf(p1, __uint_as_float(hp1 & 0xffff0000u), acc1);
            acc0 = fmaf(p2, __uint_as_float(hp2 << 16), acc0);
            acc1 = fmaf(p2, __uint_as_float(hp2 & 0xffff0000u), acc1);
            acc0 = fmaf(p3, __uint_as_float(hp3 << 16), acc0);
            acc1 = fmaf(p3, __uint_as_float(hp3 & 0xffff0000u), acc1);
        }
        for (; e < e1; ++e) {
            int j = csr[e];
            float p = EXP2(leaky(asrc[j * 4 + hd] + adx));
            unsigned int hp = hw[(size_t)j * 64 + lane];
            s += p;
            acc0 = fmaf(p, __uint_as_float(hp << 16), acc0);
            acc1 = fmaf(p, __uint_as_float(hp & 0xffff0000u), acc1);
        }
        float rs = 1.0f / s;
        const float2 pv = *(const float2*)(prev + (size_t)i * DIM + 2 * lane);
        float o0 = fmaf(acc0, rs, bb.x + pv.x);
        float o1 = fmaf(acc1, rs, bb.y + pv.y);
        *(float2*)(ypre + (size_t)i * DIM + 2 * lane) = make_float2(o0, o1);
        bsum0 += o0; bsq0 = fmaf(o0, o0, bsq0);
        bsum1 += o1; bsq1 = fmaf(o1, o1, bsq1);
    }
    __shared__ float red[4][256];
    red[0][threadIdx.x] = bsum0;
    red[1][threadIdx.x] = bsq0;
    red[2][threadIdx.x] = bsum1;
    red[3][threadIdx.x] = bsq1;
    __syncthreads();
    if (threadIdx.x < 64) {
        int t = threadIdx.x;
        float v0 = red[0][t] + red[0][t + 64] + red[0][t + 128] + red[0][t + 192];
        float v1 = red[1][t] + red[1][t + 64] + red[1][t + 128] + red[1][t + 192];
        float v2 = red[2][t] + red[2][t + 64] + red[2][t + 128] + red[2][t + 192];
        float v3 = red[3][t] + red[3][t + 64] + red[3][t + 128] + red[3][t + 192];
        atomicAdd(&stats[2 * t], v0);          // sum, channel 2t
        atomicAdd(&stats[2 * t + 1], v2);      // sum, channel 2t+1
        atomicAdd(&stats[128 + 2 * t], v1);    // sumsq, channel 2t
        atomicAdd(&stats[128 + 2 * t + 1], v3);// sumsq, channel 2t+1
    }
}

// ---------------- K7: finalize BN scale/shift ----------------
__global__ void k_bnfin(const float* __restrict__ stats, const float* __restrict__ gamma,
                        const float* __restrict__ beta, float* __restrict__ AB, int n) {
    int c = threadIdx.x;  // 128 threads
    float fn = (float)n;
    float mean = stats[c] / fn;
    float var = stats[128 + c] / fn - mean * mean;
    float a = gamma[c] * rsqrtf(var + EPS);
    AB[c] = a;
    AB[128 + c] = beta[c] - mean * a;
}

// ---------------- K8: y = relu(y*A + B), in place, float4 ----------------
__global__ __launch_bounds__(256) void k_final(float* __restrict__ y,
                                               const float* __restrict__ AB, int total4) {
    int t0 = blockIdx.x * blockDim.x + threadIdx.x;
    int stride = gridDim.x * blockDim.x;
    for (int t = t0; t < total4; t += stride) {
        float4 v = ((float4*)y)[t];
        int c0 = (t * 4) & 127;
        v.x = fmaf(v.x, AB[c0 + 0], AB[128 + c0 + 0]);
        v.y = fmaf(v.y, AB[c0 + 1], AB[128 + c0 + 1]);
        v.z = fmaf(v.z, AB[c0 + 2], AB[128 + c0 + 2]);
        v.w = fmaf(v.w, AB[c0 + 3], AB[128 + c0 + 3]);
        v.x = v.x > 0.f ? v.x : 0.f;
        v.y = v.y > 0.f ? v.y : 0.f;
        v.z = v.z > 0.f ? v.z : 0.f;
        v.w = v.w > 0.f ? v.w : 0.f;
        ((float4*)y)[t] = v;
    }
}

extern "C" void kernel_launch(void* const* d_in, const int* in_sizes, int n_in,
                              void* d_out, int out_size, void* d_ws, size_t ws_size,
                              hipStream_t stream) {
    const float* prev  = (const float*)d_in[0];
    const float* x     = (const float*)d_in[1];
    const int*   ei    = (const int*)d_in[2];
    const float* W     = (const float*)d_in[3];
    const float* att_s = (const float*)d_in[4];
    const float* att_d = (const float*)d_in[5];
    const float* bias  = (const float*)d_in[6];
    const float* gamma = (const float*)d_in[7];
    const float* beta  = (const float*)d_in[8];
    const int n = in_sizes[0] / DIM;
    const int E = in_sizes[2] / 2;
    const int* src = ei;
    const int* dst = ei + E;

    char* p = (char*)d_ws;
    auto alloc = [&](size_t bytes) {
        void* q = (void*)p;
        p += (bytes + 255) & ~(size_t)255;
        return q;
    };
    unsigned int* hpk = (unsigned int*)alloc((size_t)n * 64 * 4);
    float* asrc      = (float*)alloc((size_t)n * 4 * 4);
    float* adst      = (float*)alloc((size_t)n * 4 * 4);
    int*   deg       = (int*)alloc((size_t)(n + 1) * 4);
    int*   row_start = (int*)alloc((size_t)(n + 1) * 4);
    int*   cursor    = (int*)alloc((size_t)(n + 1) * 4);
    int*   csr       = (int*)alloc((size_t)(E + n) * 4);
    int*   bsum      = (int*)alloc(1024 * 4);
    float* stats     = (float*)alloc(256 * 4);
    float* AB        = (float*)alloc(256 * 4);
    float* yout      = (float*)d_out;

    int B = (n + 1023) / 1024;  // scan blocks (<=256 for n<=262144)
    k_init<<<dim3((n + 255) / 256), dim3(256), 0, stream>>>(deg, stats, n);
    k_gemm<<<dim3((n + 31) / 32), dim3(512), 0, stream>>>(x, W, att_s, att_d, hpk, asrc, adst, n);
    k_hist<<<dim3((E + 255) / 256), dim3(256), 0, stream>>>(dst, deg, E);
    k_scan_part<<<dim3(B), dim3(256), 0, stream>>>(deg, bsum, n);
    k_scan_tops<<<dim3(1), dim3(256), 0, stream>>>(bsum, B);
    k_scan_add<<<dim3(B), dim3(256), 0, stream>>>(deg, bsum, row_start, cursor, n, E + n);
    k_scatter<<<dim3((E + n + 255) / 256), dim3(256), 0, stream>>>(src, dst, cursor, csr, E, n);
    k_agg<<<dim3(2048), dim3(256), 0, stream>>>(hpk, asrc, adst, row_start, csr, prev, bias, yout, stats, n);
    k_bnfin<<<dim3(1), dim3(128), 0, stream>>>(stats, gamma, beta, AB, n);
    int total4 = n * DIM / 4;
    k_final<<<dim3(2048), dim3(256), 0, stream>>>(yout, AB, total4);
}

// Round 8
// 468.196 us; speedup vs baseline: 1.1480x; 1.0353x over previous
//
#include <hip/hip_runtime.h>
#include <math.h>

#define DIM 128
#define NEG 0.2f
#define EPS 1e-5f
#define LOG2E 1.4426950408889634f

#if __has_builtin(__builtin_amdgcn_exp2f)
#define EXP2(x) __builtin_amdgcn_exp2f(x)
#else
#define EXP2(x) exp2f(x)
#endif

static __device__ __forceinline__ float leaky(float a) { return a > 0.f ? a : NEG * a; }
static __device__ __forceinline__ unsigned short f2bf(float f) {
    unsigned int u = __float_as_uint(f);
    unsigned int r = (u + 0x7fffu + ((u >> 16) & 1u)) >> 16;  // RNE
    return (unsigned short)r;
}

// ---------------- K1: h = x@W, bf16x2-packed dword out, + a_src/a_dst dots --
// Lane l owns adjacent channels {2l, 2l+1} (both in head l>>4).
// att dots pre-scaled by log2(e) so k_agg can use raw v_exp_f32 (exp2).
__global__ __launch_bounds__(512, 4) void k_gemm(const float* __restrict__ x,
                                                 const float* __restrict__ W,
                                                 const float* __restrict__ att_s,
                                                 const float* __restrict__ att_d,
                                                 unsigned int* __restrict__ hpk,
                                                 float* __restrict__ asrc,
                                                 float* __restrict__ adst, int n) {
    __shared__ float2 Ws[DIM][64];   // Ws[k][c] = {W[k][2c], W[k][2c+1]}
    __shared__ float4 xs[8][4][32];  // per-wave 4 staged rows of x
    for (int idx = threadIdx.x; idx < DIM * 64; idx += 512) {
        int k = idx >> 6, c = idx & 63;
        Ws[k][c] = *(const float2*)(W + k * DIM + 2 * c);
    }
    const int w = threadIdx.x >> 6;
    const int lane = threadIdx.x & 63;
    const float as0 = att_s[2 * lane] * LOG2E, as1 = att_s[2 * lane + 1] * LOG2E;
    const float ad0 = att_d[2 * lane] * LOG2E, ad1 = att_d[2 * lane + 1] * LOG2E;
    const int r0 = blockIdx.x * 32 + w * 4;
    {   // coalesced stage: wave reads 2x 1KB contiguous (rows r0..r0+3)
        int f0 = lane, f1 = 64 + lane;
        int ra = min(r0 + (f0 >> 5), n - 1);
        int rc = min(r0 + (f1 >> 5), n - 1);
        xs[w][f0 >> 5][f0 & 31] = ((const float4*)x)[(size_t)ra * 32 + (f0 & 31)];
        xs[w][f1 >> 5][f1 & 31] = ((const float4*)x)[(size_t)rc * 32 + (f1 & 31)];
    }
    __syncthreads();
    float a00 = 0.f, a01 = 0.f, a10 = 0.f, a11 = 0.f;
    float a20 = 0.f, a21 = 0.f, a30 = 0.f, a31 = 0.f;
    for (int k4 = 0; k4 < 32; ++k4) {
        float4 xv0 = xs[w][0][k4];
        float4 xv1 = xs[w][1][k4];
        float4 xv2 = xs[w][2][k4];
        float4 xv3 = xs[w][3][k4];
#pragma unroll
        for (int kk = 0; kk < 4; ++kk) {
            float2 wv = Ws[k4 * 4 + kk][lane];
            float x0 = ((const float*)&xv0)[kk];
            float x1 = ((const float*)&xv1)[kk];
            float x2 = ((const float*)&xv2)[kk];
            float x3 = ((const float*)&xv3)[kk];
            a00 = fmaf(x0, wv.x, a00); a01 = fmaf(x0, wv.y, a01);
            a10 = fmaf(x1, wv.x, a10); a11 = fmaf(x1, wv.y, a11);
            a20 = fmaf(x2, wv.x, a20); a21 = fmaf(x2, wv.y, a21);
            a30 = fmaf(x3, wv.x, a30); a31 = fmaf(x3, wv.y, a31);
        }
    }
    float accs0[4] = {a00, a10, a20, a30};  // channel 2l
    float accs1[4] = {a01, a11, a21, a31};  // channel 2l+1
#pragma unroll
    for (int rr = 0; rr < 4; ++rr) {
        int r = r0 + rr;
        if (r >= n) break;  // wave-uniform
        float h0 = accs0[rr], h1 = accs1[rr];
        float p = h0 * as0 + h1 * as1;   // per-head partial dot (log2e-scaled)
        float q = h0 * ad0 + h1 * ad1;
#pragma unroll
        for (int m = 1; m < 16; m <<= 1) {  // reduce within 16-lane head group
            p += __shfl_xor(p, m);
            q += __shfl_xor(q, m);
        }
        hpk[(size_t)r * 64 + lane] = (unsigned int)f2bf(h0) | ((unsigned int)f2bf(h1) << 16);
        if ((lane & 15) == 0) {
            int hd = lane >> 4;
            asrc[r * 4 + hd] = p;
            adst[r * 4 + hd] = q;
        }
    }
}

// ---------------- K2: init deg=1 (self loop) and zero BN stats ----------------
__global__ void k_init(int* __restrict__ deg, float* __restrict__ stats, int n) {
    int t = blockIdx.x * blockDim.x + threadIdx.x;
    if (t < n) deg[t] = 1;
    if (t < 256) stats[t] = 0.f;
}

// ---------------- K3: histogram of dst ----------------
__global__ void k_hist(const int* __restrict__ dst, int* __restrict__ deg, int E) {
    int t = blockIdx.x * blockDim.x + threadIdx.x;
    if (t < E) atomicAdd(&deg[dst[t]], 1);
}

// ---------------- K4abc: device-wide exclusive scan of deg (1024 elems/block) --
__global__ __launch_bounds__(256) void k_scan_part(const int* __restrict__ deg,
                                                   int* __restrict__ bsum, int n) {
    int idx = blockIdx.x * 1024 + threadIdx.x * 4;
    int4 v = {0, 0, 0, 0};
    if (idx + 3 < n) v = *(const int4*)(deg + idx);
    else {
        if (idx + 0 < n) v.x = deg[idx + 0];
        if (idx + 1 < n) v.y = deg[idx + 1];
        if (idx + 2 < n) v.z = deg[idx + 2];
    }
    int s = v.x + v.y + v.z + v.w;
#pragma unroll
    for (int m = 1; m < 64; m <<= 1) s += __shfl_xor(s, m);
    __shared__ int ws[4];
    if ((threadIdx.x & 63) == 0) ws[threadIdx.x >> 6] = s;
    __syncthreads();
    if (threadIdx.x == 0) bsum[blockIdx.x] = ws[0] + ws[1] + ws[2] + ws[3];
}

__global__ __launch_bounds__(256) void k_scan_tops(int* __restrict__ bsum, int B) {
    __shared__ int lds[256];
    int t = threadIdx.x;
    int v = (t < B) ? bsum[t] : 0;
    lds[t] = v;
    __syncthreads();
    int acc = v;
    for (int ofs = 1; ofs < 256; ofs <<= 1) {
        int u = (t >= ofs) ? lds[t - ofs] : 0;
        __syncthreads();
        acc += u;
        lds[t] = acc;
        __syncthreads();
    }
    if (t < B) bsum[t] = acc - v;  // exclusive block offsets (in place)
}

__global__ __launch_bounds__(256) void k_scan_add(const int* __restrict__ deg,
                                                  const int* __restrict__ bsum,
                                                  int* __restrict__ row_start,
                                                  int* __restrict__ cursor, int n, int total) {
    int t = threadIdx.x;
    int idx = blockIdx.x * 1024 + t * 4;
    int4 v = {0, 0, 0, 0};
    if (idx + 3 < n) v = *(const int4*)(deg + idx);
    else {
        if (idx + 0 < n) v.x = deg[idx + 0];
        if (idx + 1 < n) v.y = deg[idx + 1];
        if (idx + 2 < n) v.z = deg[idx + 2];
    }
    int s = v.x + v.y + v.z + v.w;
    __shared__ int lds[256];
    lds[t] = s;
    __syncthreads();
    int acc = s;
    for (int ofs = 1; ofs < 256; ofs <<= 1) {
        int u = (t >= ofs) ? lds[t - ofs] : 0;
        __syncthreads();
        acc += u;
        lds[t] = acc;
        __syncthreads();
    }
    int excl = bsum[blockIdx.x] + acc - s;
    int4 rs;
    rs.x = excl;
    rs.y = rs.x + v.x;
    rs.z = rs.y + v.y;
    rs.w = rs.z + v.z;
    if (idx + 3 < n) {
        *(int4*)(row_start + idx) = rs;
        *(int4*)(cursor + idx) = rs;
    } else {
        if (idx + 0 < n) { row_start[idx + 0] = rs.x; cursor[idx + 0] = rs.x; }
        if (idx + 1 < n) { row_start[idx + 1] = rs.y; cursor[idx + 1] = rs.y; }
        if (idx + 2 < n) { row_start[idx + 2] = rs.z; cursor[idx + 2] = rs.z; }
    }
    if (blockIdx.x == 0 && t == 0) row_start[n] = total;
}

// ---------------- K5: scatter edges (and self loops) into CSR ----------------
__global__ void k_scatter(const int* __restrict__ src, const int* __restrict__ dst,
                          int* __restrict__ cursor, int* __restrict__ csr, int E, int n) {
    int t = blockIdx.x * blockDim.x + threadIdx.x;
    if (t < E) {
        int d = dst[t];
        int slot = atomicAdd(&cursor[d], 1);
        csr[slot] = src[t];
    } else if (t < E + n) {
        int i = t - E;
        int slot = atomicAdd(&cursor[i], 1);
        csr[slot] = i;
    }
}

// ---------------- K6: per-dst-node single-pass max-free softmax aggregation,
//                      8-edge batches with tail MASKING (no serial remainder):
//                      clamped index keeps 8 gathers in flight every batch;
//                      invalid edges contribute p=0. One wave per node.
__global__ __launch_bounds__(256) void k_agg(const unsigned int* __restrict__ hw,
                                             const float* __restrict__ asrc,
                                             const float* __restrict__ adst,
                                             const int* __restrict__ row_start,
                                             const int* __restrict__ csr,
                                             const float* __restrict__ prev,
                                             const float* __restrict__ bias,
                                             float* __restrict__ ypre,
                                             float* __restrict__ stats, int n) {
    const int lane = threadIdx.x & 63;
    const int hd = lane >> 4;  // head for channels {2l, 2l+1}
    int wave = blockIdx.x * 4 + (threadIdx.x >> 6);
    int nw = gridDim.x * 4;
    const float2 bb = *(const float2*)(bias + 2 * lane);
    float bsum0 = 0.f, bsq0 = 0.f, bsum1 = 0.f, bsq1 = 0.f;
    for (int i0 = wave; i0 < n; i0 += nw) {
        int i = __builtin_amdgcn_readfirstlane(i0);
        int e0 = row_start[i], e1 = row_start[i + 1];
        const float adx = adst[i * 4 + hd];
        float s = 0.f, acc0 = 0.f, acc1 = 0.f;
        for (int e = e0; e < e1; e += 8) {
            int j[8];
            float g[8];
            unsigned int hp[8];
#pragma unroll
            for (int r = 0; r < 8; ++r) j[r] = csr[min(e + r, e1 - 1)];
#pragma unroll
            for (int r = 0; r < 8; ++r) g[r] = asrc[j[r] * 4 + hd];
#pragma unroll
            for (int r = 0; r < 8; ++r) hp[r] = hw[(size_t)j[r] * 64 + lane];
#pragma unroll
            for (int r = 0; r < 8; ++r) {
                float p = (e + r < e1) ? EXP2(leaky(g[r] + adx)) : 0.f;
                s += p;
                acc0 = fmaf(p, __uint_as_float(hp[r] << 16), acc0);
                acc1 = fmaf(p, __uint_as_float(hp[r] & 0xffff0000u), acc1);
            }
        }
        float rs = 1.0f / s;
        const float2 pv = *(const float2*)(prev + (size_t)i * DIM + 2 * lane);
        float o0 = fmaf(acc0, rs, bb.x + pv.x);
        float o1 = fmaf(acc1, rs, bb.y + pv.y);
        *(float2*)(ypre + (size_t)i * DIM + 2 * lane) = make_float2(o0, o1);
        bsum0 += o0; bsq0 = fmaf(o0, o0, bsq0);
        bsum1 += o1; bsq1 = fmaf(o1, o1, bsq1);
    }
    __shared__ float red[4][256];
    red[0][threadIdx.x] = bsum0;
    red[1][threadIdx.x] = bsq0;
    red[2][threadIdx.x] = bsum1;
    red[3][threadIdx.x] = bsq1;
    __syncthreads();
    if (threadIdx.x < 64) {
        int t = threadIdx.x;
        float v0 = red[0][t] + red[0][t + 64] + red[0][t + 128] + red[0][t + 192];
        float v1 = red[1][t] + red[1][t + 64] + red[1][t + 128] + red[1][t + 192];
        float v2 = red[2][t] + red[2][t + 64] + red[2][t + 128] + red[2][t + 192];
        float v3 = red[3][t] + red[3][t + 64] + red[3][t + 128] + red[3][t + 192];
        atomicAdd(&stats[2 * t], v0);          // sum, channel 2t
        atomicAdd(&stats[2 * t + 1], v2);      // sum, channel 2t+1
        atomicAdd(&stats[128 + 2 * t], v1);    // sumsq, channel 2t
        atomicAdd(&stats[128 + 2 * t + 1], v3);// sumsq, channel 2t+1
    }
}

// ---------------- K7: finalize BN scale/shift ----------------
__global__ void k_bnfin(const float* __restrict__ stats, const float* __restrict__ gamma,
                        const float* __restrict__ beta, float* __restrict__ AB, int n) {
    int c = threadIdx.x;  // 128 threads
    float fn = (float)n;
    float mean = stats[c] / fn;
    float var = stats[128 + c] / fn - mean * mean;
    float a = gamma[c] * rsqrtf(var + EPS);
    AB[c] = a;
    AB[128 + c] = beta[c] - mean * a;
}

// ---------------- K8: y = relu(y*A + B), in place, float4 ----------------
__global__ __launch_bounds__(256) void k_final(float* __restrict__ y,
                                               const float* __restrict__ AB, int total4) {
    int t0 = blockIdx.x * blockDim.x + threadIdx.x;
    int stride = gridDim.x * blockDim.x;
    for (int t = t0; t < total4; t += stride) {
        float4 v = ((float4*)y)[t];
        int c0 = (t * 4) & 127;
        v.x = fmaf(v.x, AB[c0 + 0], AB[128 + c0 + 0]);
        v.y = fmaf(v.y, AB[c0 + 1], AB[128 + c0 + 1]);
        v.z = fmaf(v.z, AB[c0 + 2], AB[128 + c0 + 2]);
        v.w = fmaf(v.w, AB[c0 + 3], AB[128 + c0 + 3]);
        v.x = v.x > 0.f ? v.x : 0.f;
        v.y = v.y > 0.f ? v.y : 0.f;
        v.z = v.z > 0.f ? v.z : 0.f;
        v.w = v.w > 0.f ? v.w : 0.f;
        ((float4*)y)[t] = v;
    }
}

extern "C" void kernel_launch(void* const* d_in, const int* in_sizes, int n_in,
                              void* d_out, int out_size, void* d_ws, size_t ws_size,
                              hipStream_t stream) {
    const float* prev  = (const float*)d_in[0];
    const float* x     = (const float*)d_in[1];
    const int*   ei    = (const int*)d_in[2];
    const float* W     = (const float*)d_in[3];
    const float* att_s = (const float*)d_in[4];
    const float* att_d = (const float*)d_in[5];
    const float* bias  = (const float*)d_in[6];
    const float* gamma = (const float*)d_in[7];
    const float* beta  = (const float*)d_in[8];
    const int n = in_sizes[0] / DIM;
    const int E = in_sizes[2] / 2;
    const int* src = ei;
    const int* dst = ei + E;

    char* p = (char*)d_ws;
    auto alloc = [&](size_t bytes) {
        void* q = (void*)p;
        p += (bytes + 255) & ~(size_t)255;
        return q;
    };
    unsigned int* hpk = (unsigned int*)alloc((size_t)n * 64 * 4);
    float* asrc      = (float*)alloc((size_t)n * 4 * 4);
    float* adst      = (float*)alloc((size_t)n * 4 * 4);
    int*   deg       = (int*)alloc((size_t)(n + 1) * 4);
    int*   row_start = (int*)alloc((size_t)(n + 1) * 4);
    int*   cursor    = (int*)alloc((size_t)(n + 1) * 4);
    int*   csr       = (int*)alloc((size_t)(E + n) * 4);
    int*   bsum      = (int*)alloc(1024 * 4);
    float* stats     = (float*)alloc(256 * 4);
    float* AB        = (float*)alloc(256 * 4);
    float* yout      = (float*)d_out;

    int B = (n + 1023) / 1024;  // scan blocks (<=256 for n<=262144)
    k_init<<<dim3((n + 255) / 256), dim3(256), 0, stream>>>(deg, stats, n);
    k_gemm<<<dim3((n + 31) / 32), dim3(512), 0, stream>>>(x, W, att_s, att_d, hpk, asrc, adst, n);
    k_hist<<<dim3((E + 255) / 256), dim3(256), 0, stream>>>(dst, deg, E);
    k_scan_part<<<dim3(B), dim3(256), 0, stream>>>(deg, bsum, n);
    k_scan_tops<<<dim3(1), dim3(256), 0, stream>>>(bsum, B);
    k_scan_add<<<dim3(B), dim3(256), 0, stream>>>(deg, bsum, row_start, cursor, n, E + n);
    k_scatter<<<dim3((E + n + 255) / 256), dim3(256), 0, stream>>>(src, dst, cursor, csr, E, n);
    k_agg<<<dim3(2048), dim3(256), 0, stream>>>(hpk, asrc, adst, row_start, csr, prev, bias, yout, stats, n);
    k_bnfin<<<dim3(1), dim3(128), 0, stream>>>(stats, gamma, beta, AB, n);
    int total4 = n * DIM / 4;
    k_final<<<dim3(2048), dim3(256), 0, stream>>>(yout, AB, total4);
}

// Round 9
// 377.738 us; speedup vs baseline: 1.4229x; 1.2395x over previous
//
#include <hip/hip_runtime.h>
#include <math.h>

#define DIM 128
#define NEG 0.2f
#define EPS 1e-5f
#define LOG2E 1.4426950408889634f

#if __has_builtin(__builtin_amdgcn_exp2f)
#define EXP2(x) __builtin_amdgcn_exp2f(x)
#else
#define EXP2(x) exp2f(x)
#endif

typedef __attribute__((ext_vector_type(8))) short short8v;  // bf16x8 MFMA frag
typedef __attribute__((ext_vector_type(4))) float f32x4;

static __device__ __forceinline__ float leaky(float a) { return a > 0.f ? a : NEG * a; }
static __device__ __forceinline__ unsigned short f2bf(float f) {
    unsigned int u = __float_as_uint(f);
    unsigned int r = (u + 0x7fffu + ((u >> 16) & 1u)) >> 16;  // RNE
    return (unsigned short)r;
}

// ---------------- K1: h = x@W via MFMA bf16. Block=256 (4 waves).
// Wave w owns head w = cols [32w, 32w+32). B-frags (W) live in registers for
// the whole kernel. Per chunk: 16 rows staged as bf16 in LDS, 8 MFMAs/wave.
// hpk word l of row r = channels {c, c+16}, c = 32*(l>>4) + (l&15).
// asrc/adst = per-head att dots, pre-scaled by log2(e).
__global__ __launch_bounds__(256) void k_gemm(const float* __restrict__ x,
                                              const float* __restrict__ W,
                                              const float* __restrict__ att_s,
                                              const float* __restrict__ att_d,
                                              unsigned int* __restrict__ hpk,
                                              float* __restrict__ asrc,
                                              float* __restrict__ adst, int n) {
    __shared__ __align__(16) unsigned short xs[16][136];  // 16 rows bf16, padded
    const int tid = threadIdx.x;
    const int w = tid >> 6;    // wave = head
    const int lane = tid & 63;
    const int lm = lane & 15;  // m (A row) / n (B col) index
    const int lk = lane >> 4;  // k-group
    // --- B fragments from global W, once per block ---
    // B[k][n]: n = lane&15, k = 8*(lane>>4) + j (+32 per k-chunk q)
    short8v bfrag[2][4];
#pragma unroll
    for (int ct = 0; ct < 2; ++ct) {
        int c = w * 32 + ct * 16 + lm;
#pragma unroll
        for (int q = 0; q < 4; ++q) {
            short8v f;
#pragma unroll
            for (int j = 0; j < 8; ++j) {
                int k = q * 32 + lk * 8 + j;
                f[j] = (short)f2bf(W[k * DIM + c]);
            }
            bfrag[ct][q] = f;
        }
    }
    const float asv0 = att_s[w * 32 + lm] * LOG2E;
    const float asv1 = att_s[w * 32 + 16 + lm] * LOG2E;
    const float adv0 = att_d[w * 32 + lm] * LOG2E;
    const float adv1 = att_d[w * 32 + 16 + lm] * LOG2E;

    const int nchunk = (n + 15) >> 4;
    for (int chunk = blockIdx.x; chunk < nchunk; chunk += gridDim.x) {
        const int r0 = chunk * 16;
        {   // stage 16 rows of x -> bf16 LDS (coalesced 32B/thread)
            int row = tid >> 4;
            int c8 = (tid & 15) * 8;
            int rg = min(r0 + row, n - 1);
            const float4* xp = (const float4*)(x + (size_t)rg * DIM + c8);
            float4 v0 = xp[0], v1 = xp[1];
            short8v t;
            t[0] = (short)f2bf(v0.x); t[1] = (short)f2bf(v0.y);
            t[2] = (short)f2bf(v0.z); t[3] = (short)f2bf(v0.w);
            t[4] = (short)f2bf(v1.x); t[5] = (short)f2bf(v1.y);
            t[6] = (short)f2bf(v1.z); t[7] = (short)f2bf(v1.w);
            *(short8v*)(&xs[row][c8]) = t;
        }
        __syncthreads();
        f32x4 acc0 = {0.f, 0.f, 0.f, 0.f}, acc1 = {0.f, 0.f, 0.f, 0.f};
#pragma unroll
        for (int q = 0; q < 4; ++q) {
            // A[m][k]: m = lane&15, k = 8*(lane>>4)+j (+32q)
            short8v a = *(const short8v*)(&xs[lm][q * 32 + lk * 8]);
            acc0 = __builtin_amdgcn_mfma_f32_16x16x32_bf16(a, bfrag[0][q], acc0, 0, 0, 0);
            acc1 = __builtin_amdgcn_mfma_f32_16x16x32_bf16(a, bfrag[1][q], acc1, 0, 0, 0);
        }
        __syncthreads();  // xs consumed; safe to restage next chunk
        // att dots: lane holds rows 4*lk+j, cols {32w+lm, 32w+16+lm}
        float ps[4], qs[4];
#pragma unroll
        for (int j = 0; j < 4; ++j) {
            ps[j] = acc0[j] * asv0 + acc1[j] * asv1;
            qs[j] = acc0[j] * adv0 + acc1[j] * adv1;
        }
#pragma unroll
        for (int m = 1; m < 16; m <<= 1) {
#pragma unroll
            for (int j = 0; j < 4; ++j) {
                ps[j] += __shfl_xor(ps[j], m);
                qs[j] += __shfl_xor(qs[j], m);
            }
        }
#pragma unroll
        for (int j = 0; j < 4; ++j) {
            int r = r0 + 4 * lk + j;
            if (r < n) {
                hpk[(size_t)r * 64 + 16 * w + lm] =
                    (unsigned int)f2bf(acc0[j]) | ((unsigned int)f2bf(acc1[j]) << 16);
                if (lm == 0) {
                    asrc[r * 4 + w] = ps[j];
                    adst[r * 4 + w] = qs[j];
                }
            }
        }
    }
}

// ---------------- K2: init deg=1 (self loop) and zero BN stats ----------------
__global__ void k_init(int* __restrict__ deg, float* __restrict__ stats, int n) {
    int t = blockIdx.x * blockDim.x + threadIdx.x;
    if (t < n) deg[t] = 1;
    if (t < 256) stats[t] = 0.f;
}

// ---------------- K3: histogram of dst ----------------
__global__ void k_hist(const int* __restrict__ dst, int* __restrict__ deg, int E) {
    int t = blockIdx.x * blockDim.x + threadIdx.x;
    if (t < E) atomicAdd(&deg[dst[t]], 1);
}

// ---------------- K4abc: device-wide exclusive scan of deg (1024 elems/block) --
__global__ __launch_bounds__(256) void k_scan_part(const int* __restrict__ deg,
                                                   int* __restrict__ bsum, int n) {
    int idx = blockIdx.x * 1024 + threadIdx.x * 4;
    int4 v = {0, 0, 0, 0};
    if (idx + 3 < n) v = *(const int4*)(deg + idx);
    else {
        if (idx + 0 < n) v.x = deg[idx + 0];
        if (idx + 1 < n) v.y = deg[idx + 1];
        if (idx + 2 < n) v.z = deg[idx + 2];
    }
    int s = v.x + v.y + v.z + v.w;
#pragma unroll
    for (int m = 1; m < 64; m <<= 1) s += __shfl_xor(s, m);
    __shared__ int ws[4];
    if ((threadIdx.x & 63) == 0) ws[threadIdx.x >> 6] = s;
    __syncthreads();
    if (threadIdx.x == 0) bsum[blockIdx.x] = ws[0] + ws[1] + ws[2] + ws[3];
}

__global__ __launch_bounds__(256) void k_scan_tops(int* __restrict__ bsum, int B) {
    __shared__ int lds[256];
    int t = threadIdx.x;
    int v = (t < B) ? bsum[t] : 0;
    lds[t] = v;
    __syncthreads();
    int acc = v;
    for (int ofs = 1; ofs < 256; ofs <<= 1) {
        int u = (t >= ofs) ? lds[t - ofs] : 0;
        __syncthreads();
        acc += u;
        lds[t] = acc;
        __syncthreads();
    }
    if (t < B) bsum[t] = acc - v;  // exclusive block offsets (in place)
}

__global__ __launch_bounds__(256) void k_scan_add(const int* __restrict__ deg,
                                                  const int* __restrict__ bsum,
                                                  int* __restrict__ row_start,
                                                  int* __restrict__ cursor, int n, int total) {
    int t = threadIdx.x;
    int idx = blockIdx.x * 1024 + t * 4;
    int4 v = {0, 0, 0, 0};
    if (idx + 3 < n) v = *(const int4*)(deg + idx);
    else {
        if (idx + 0 < n) v.x = deg[idx + 0];
        if (idx + 1 < n) v.y = deg[idx + 1];
        if (idx + 2 < n) v.z = deg[idx + 2];
    }
    int s = v.x + v.y + v.z + v.w;
    __shared__ int lds[256];
    lds[t] = s;
    __syncthreads();
    int acc = s;
    for (int ofs = 1; ofs < 256; ofs <<= 1) {
        int u = (t >= ofs) ? lds[t - ofs] : 0;
        __syncthreads();
        acc += u;
        lds[t] = acc;
        __syncthreads();
    }
    int excl = bsum[blockIdx.x] + acc - s;
    int4 rs;
    rs.x = excl;
    rs.y = rs.x + v.x;
    rs.z = rs.y + v.y;
    rs.w = rs.z + v.z;
    if (idx + 3 < n) {
        *(int4*)(row_start + idx) = rs;
        *(int4*)(cursor + idx) = rs;
    } else {
        if (idx + 0 < n) { row_start[idx + 0] = rs.x; cursor[idx + 0] = rs.x; }
        if (idx + 1 < n) { row_start[idx + 1] = rs.y; cursor[idx + 1] = rs.y; }
        if (idx + 2 < n) { row_start[idx + 2] = rs.z; cursor[idx + 2] = rs.z; }
    }
    if (blockIdx.x == 0 && t == 0) row_start[n] = total;
}

// ---------------- K5: scatter edges (and self loops) into CSR ----------------
__global__ void k_scatter(const int* __restrict__ src, const int* __restrict__ dst,
                          int* __restrict__ cursor, int* __restrict__ csr, int E, int n) {
    int t = blockIdx.x * blockDim.x + threadIdx.x;
    if (t < E) {
        int d = dst[t];
        int slot = atomicAdd(&cursor[d], 1);
        csr[slot] = src[t];
    } else if (t < E + n) {
        int i = t - E;
        int slot = atomicAdd(&cursor[i], 1);
        csr[slot] = i;
    }
}

// ---------------- K6: per-dst-node single-pass max-free softmax aggregation,
//                      16-edge clamp-masked batches (32 gathers in flight).
//                      Lane l: channels {c, c+16}, c = 32*(l>>4)+(l&15); head l>>4.
__global__ __launch_bounds__(256) void k_agg(const unsigned int* __restrict__ hw,
                                             const float* __restrict__ asrc,
                                             const float* __restrict__ adst,
                                             const int* __restrict__ row_start,
                                             const int* __restrict__ csr,
                                             const float* __restrict__ prev,
                                             const float* __restrict__ bias,
                                             float* __restrict__ ypre,
                                             float* __restrict__ stats, int n) {
    const int lane = threadIdx.x & 63;
    const int hd = lane >> 4;                 // head
    const int ch = 32 * hd + (lane & 15);     // channel pair {ch, ch+16}
    int wave = blockIdx.x * 4 + (threadIdx.x >> 6);
    int nw = gridDim.x * 4;
    const float bb0 = bias[ch], bb1 = bias[ch + 16];
    float bsum0 = 0.f, bsq0 = 0.f, bsum1 = 0.f, bsq1 = 0.f;
    for (int i0 = wave; i0 < n; i0 += nw) {
        int i = __builtin_amdgcn_readfirstlane(i0);
        int e0 = row_start[i], e1 = row_start[i + 1];
        const float adx = adst[i * 4 + hd];
        float s = 0.f, acc0 = 0.f, acc1 = 0.f;
        for (int e = e0; e < e1; e += 16) {
            int j[16];
            float g[16];
            unsigned int hp[16];
#pragma unroll
            for (int r = 0; r < 16; ++r) j[r] = csr[min(e + r, e1 - 1)];
#pragma unroll
            for (int r = 0; r < 16; ++r) g[r] = asrc[j[r] * 4 + hd];
#pragma unroll
            for (int r = 0; r < 16; ++r) hp[r] = hw[(size_t)j[r] * 64 + lane];
#pragma unroll
            for (int r = 0; r < 16; ++r) {
                float p = (e + r < e1) ? EXP2(leaky(g[r] + adx)) : 0.f;
                s += p;
                acc0 = fmaf(p, __uint_as_float(hp[r] << 16), acc0);
                acc1 = fmaf(p, __uint_as_float(hp[r] & 0xffff0000u), acc1);
            }
        }
        float rs = 1.0f / s;
        size_t base = (size_t)i * DIM;
        float o0 = fmaf(acc0, rs, bb0 + prev[base + ch]);
        float o1 = fmaf(acc1, rs, bb1 + prev[base + ch + 16]);
        ypre[base + ch] = o0;
        ypre[base + ch + 16] = o1;
        bsum0 += o0; bsq0 = fmaf(o0, o0, bsq0);
        bsum1 += o1; bsq1 = fmaf(o1, o1, bsq1);
    }
    __shared__ float red[4][256];
    red[0][threadIdx.x] = bsum0;
    red[1][threadIdx.x] = bsq0;
    red[2][threadIdx.x] = bsum1;
    red[3][threadIdx.x] = bsq1;
    __syncthreads();
    if (threadIdx.x < 64) {
        int t = threadIdx.x;
        int c = 32 * (t >> 4) + (t & 15);
        float v0 = red[0][t] + red[0][t + 64] + red[0][t + 128] + red[0][t + 192];
        float v1 = red[1][t] + red[1][t + 64] + red[1][t + 128] + red[1][t + 192];
        float v2 = red[2][t] + red[2][t + 64] + red[2][t + 128] + red[2][t + 192];
        float v3 = red[3][t] + red[3][t + 64] + red[3][t + 128] + red[3][t + 192];
        atomicAdd(&stats[c], v0);             // sum, channel c
        atomicAdd(&stats[c + 16], v2);        // sum, channel c+16
        atomicAdd(&stats[128 + c], v1);       // sumsq, channel c
        atomicAdd(&stats[128 + c + 16], v3);  // sumsq, channel c+16
    }
}

// ---------------- K7: finalize BN scale/shift ----------------
__global__ void k_bnfin(const float* __restrict__ stats, const float* __restrict__ gamma,
                        const float* __restrict__ beta, float* __restrict__ AB, int n) {
    int c = threadIdx.x;  // 128 threads
    float fn = (float)n;
    float mean = stats[c] / fn;
    float var = stats[128 + c] / fn - mean * mean;
    float a = gamma[c] * rsqrtf(var + EPS);
    AB[c] = a;
    AB[128 + c] = beta[c] - mean * a;
}

// ---------------- K8: y = relu(y*A + B), in place, float4 ----------------
__global__ __launch_bounds__(256) void k_final(float* __restrict__ y,
                                               const float* __restrict__ AB, int total4) {
    int t0 = blockIdx.x * blockDim.x + threadIdx.x;
    int stride = gridDim.x * blockDim.x;
    for (int t = t0; t < total4; t += stride) {
        float4 v = ((float4*)y)[t];
        int c0 = (t * 4) & 127;
        v.x = fmaf(v.x, AB[c0 + 0], AB[128 + c0 + 0]);
        v.y = fmaf(v.y, AB[c0 + 1], AB[128 + c0 + 1]);
        v.z = fmaf(v.z, AB[c0 + 2], AB[128 + c0 + 2]);
        v.w = fmaf(v.w, AB[c0 + 3], AB[128 + c0 + 3]);
        v.x = v.x > 0.f ? v.x : 0.f;
        v.y = v.y > 0.f ? v.y : 0.f;
        v.z = v.z > 0.f ? v.z : 0.f;
        v.w = v.w > 0.f ? v.w : 0.f;
        ((float4*)y)[t] = v;
    }
}

extern "C" void kernel_launch(void* const* d_in, const int* in_sizes, int n_in,
                              void* d_out, int out_size, void* d_ws, size_t ws_size,
                              hipStream_t stream) {
    const float* prev  = (const float*)d_in[0];
    const float* x     = (const float*)d_in[1];
    const int*   ei    = (const int*)d_in[2];
    const float* W     = (const float*)d_in[3];
    const float* att_s = (const float*)d_in[4];
    const float* att_d = (const float*)d_in[5];
    const float* bias  = (const float*)d_in[6];
    const float* gamma = (const float*)d_in[7];
    const float* beta  = (const float*)d_in[8];
    const int n = in_sizes[0] / DIM;
    const int E = in_sizes[2] / 2;
    const int* src = ei;
    const int* dst = ei + E;

    char* p = (char*)d_ws;
    auto alloc = [&](size_t bytes) {
        void* q = (void*)p;
        p += (bytes + 255) & ~(size_t)255;
        return q;
    };
    unsigned int* hpk = (unsigned int*)alloc((size_t)n * 64 * 4);
    float* asrc      = (float*)alloc((size_t)n * 4 * 4);
    float* adst      = (float*)alloc((size_t)n * 4 * 4);
    int*   deg       = (int*)alloc((size_t)(n + 1) * 4);
    int*   row_start = (int*)alloc((size_t)(n + 1) * 4);
    int*   cursor    = (int*)alloc((size_t)(n + 1) * 4);
    int*   csr       = (int*)alloc((size_t)(E + n) * 4);
    int*   bsum      = (int*)alloc(1024 * 4);
    float* stats     = (float*)alloc(256 * 4);
    float* AB        = (float*)alloc(256 * 4);
    float* yout      = (float*)d_out;

    int B = (n + 1023) / 1024;  // scan blocks (<=256 for n<=262144)
    k_init<<<dim3((n + 255) / 256), dim3(256), 0, stream>>>(deg, stats, n);
    k_gemm<<<dim3(2048), dim3(256), 0, stream>>>(x, W, att_s, att_d, hpk, asrc, adst, n);
    k_hist<<<dim3((E + 255) / 256), dim3(256), 0, stream>>>(dst, deg, E);
    k_scan_part<<<dim3(B), dim3(256), 0, stream>>>(deg, bsum, n);
    k_scan_tops<<<dim3(1), dim3(256), 0, stream>>>(bsum, B);
    k_scan_add<<<dim3(B), dim3(256), 0, stream>>>(deg, bsum, row_start, cursor, n, E + n);
    k_scatter<<<dim3((E + n + 255) / 256), dim3(256), 0, stream>>>(src, dst, cursor, csr, E, n);
    k_agg<<<dim3(2048), dim3(256), 0, stream>>>(hpk, asrc, adst, row_start, csr, prev, bias, yout, stats, n);
    k_bnfin<<<dim3(1), dim3(128), 0, stream>>>(stats, gamma, beta, AB, n);
    int total4 = n * DIM / 4;
    k_final<<<dim3(2048), dim3(256), 0, stream>>>(yout, AB, total4);
}

// Round 10
// 372.832 us; speedup vs baseline: 1.4416x; 1.0132x over previous
//
#include <hip/hip_runtime.h>
#include <math.h>

#define DIM 128
#define NEG 0.2f
#define EPS 1e-5f
#define LOG2E 1.4426950408889634f

#if __has_builtin(__builtin_amdgcn_exp2f)
#define EXP2(x) __builtin_amdgcn_exp2f(x)
#else
#define EXP2(x) exp2f(x)
#endif

typedef __attribute__((ext_vector_type(8))) short short8v;  // bf16x8 MFMA frag
typedef __attribute__((ext_vector_type(4))) float f32x4;

static __device__ __forceinline__ float leaky(float a) { return a > 0.f ? a : NEG * a; }
static __device__ __forceinline__ unsigned short f2bf(float f) {
    unsigned int u = __float_as_uint(f);
    unsigned int r = (u + 0x7fffu + ((u >> 16) & 1u)) >> 16;  // RNE
    return (unsigned short)r;
}

// ---------------- K1: h = x@W via MFMA bf16. Block=256 (4 waves).
// Wave w owns head w = cols [32w, 32w+32). B-frags (W) live in registers for
// the whole kernel. Per chunk: 16 rows staged as bf16 in LDS, 8 MFMAs/wave.
// hpk word l of row r = channels {c, c+16}, c = 32*(l>>4) + (l&15).
__global__ __launch_bounds__(256) void k_gemm(const float* __restrict__ x,
                                              const float* __restrict__ W,
                                              const float* __restrict__ att_s,
                                              const float* __restrict__ att_d,
                                              unsigned int* __restrict__ hpk,
                                              float* __restrict__ asrc,
                                              float* __restrict__ adst, int n) {
    __shared__ __align__(16) unsigned short xs[16][136];  // 16 rows bf16, padded
    const int tid = threadIdx.x;
    const int w = tid >> 6;    // wave = head
    const int lane = tid & 63;
    const int lm = lane & 15;  // m (A row) / n (B col) index
    const int lk = lane >> 4;  // k-group
    short8v bfrag[2][4];
#pragma unroll
    for (int ct = 0; ct < 2; ++ct) {
        int c = w * 32 + ct * 16 + lm;
#pragma unroll
        for (int q = 0; q < 4; ++q) {
            short8v f;
#pragma unroll
            for (int j = 0; j < 8; ++j) {
                int k = q * 32 + lk * 8 + j;
                f[j] = (short)f2bf(W[k * DIM + c]);
            }
            bfrag[ct][q] = f;
        }
    }
    const float asv0 = att_s[w * 32 + lm] * LOG2E;
    const float asv1 = att_s[w * 32 + 16 + lm] * LOG2E;
    const float adv0 = att_d[w * 32 + lm] * LOG2E;
    const float adv1 = att_d[w * 32 + 16 + lm] * LOG2E;

    const int nchunk = (n + 15) >> 4;
    for (int chunk = blockIdx.x; chunk < nchunk; chunk += gridDim.x) {
        const int r0 = chunk * 16;
        {   // stage 16 rows of x -> bf16 LDS (coalesced 32B/thread)
            int row = tid >> 4;
            int c8 = (tid & 15) * 8;
            int rg = min(r0 + row, n - 1);
            const float4* xp = (const float4*)(x + (size_t)rg * DIM + c8);
            float4 v0 = xp[0], v1 = xp[1];
            short8v t;
            t[0] = (short)f2bf(v0.x); t[1] = (short)f2bf(v0.y);
            t[2] = (short)f2bf(v0.z); t[3] = (short)f2bf(v0.w);
            t[4] = (short)f2bf(v1.x); t[5] = (short)f2bf(v1.y);
            t[6] = (short)f2bf(v1.z); t[7] = (short)f2bf(v1.w);
            *(short8v*)(&xs[row][c8]) = t;
        }
        __syncthreads();
        f32x4 acc0 = {0.f, 0.f, 0.f, 0.f}, acc1 = {0.f, 0.f, 0.f, 0.f};
#pragma unroll
        for (int q = 0; q < 4; ++q) {
            short8v a = *(const short8v*)(&xs[lm][q * 32 + lk * 8]);
            acc0 = __builtin_amdgcn_mfma_f32_16x16x32_bf16(a, bfrag[0][q], acc0, 0, 0, 0);
            acc1 = __builtin_amdgcn_mfma_f32_16x16x32_bf16(a, bfrag[1][q], acc1, 0, 0, 0);
        }
        __syncthreads();  // xs consumed; safe to restage next chunk
        float ps[4], qs[4];
#pragma unroll
        for (int j = 0; j < 4; ++j) {
            ps[j] = acc0[j] * asv0 + acc1[j] * asv1;
            qs[j] = acc0[j] * adv0 + acc1[j] * adv1;
        }
#pragma unroll
        for (int m = 1; m < 16; m <<= 1) {
#pragma unroll
            for (int j = 0; j < 4; ++j) {
                ps[j] += __shfl_xor(ps[j], m);
                qs[j] += __shfl_xor(qs[j], m);
            }
        }
#pragma unroll
        for (int j = 0; j < 4; ++j) {
            int r = r0 + 4 * lk + j;
            if (r < n) {
                hpk[(size_t)r * 64 + 16 * w + lm] =
                    (unsigned int)f2bf(acc0[j]) | ((unsigned int)f2bf(acc1[j]) << 16);
                if (lm == 0) {
                    asrc[r * 4 + w] = ps[j];
                    adst[r * 4 + w] = qs[j];
                }
            }
        }
    }
}

// ---------------- K2: init deg16=1 (self loop, line-padded) + zero BN stats --
__global__ void k_init(int* __restrict__ deg16, float* __restrict__ stats, int n) {
    int t = blockIdx.x * blockDim.x + threadIdx.x;
    if (t < n) deg16[t << 4] = 1;
    if (t < 256) stats[t] = 0.f;
}

// ---------------- K3: histogram of dst (one counter per 64B line) ----------
__global__ void k_hist(const int* __restrict__ dst, int* __restrict__ deg16, int E) {
    int t = blockIdx.x * blockDim.x + threadIdx.x;
    if (t < E) atomicAdd(&deg16[dst[t] << 4], 1);
}

// ---------------- K4abc: device-wide exclusive scan of deg16 (1024/block) ----
__global__ __launch_bounds__(256) void k_scan_part(const int* __restrict__ deg16,
                                                   int* __restrict__ bsum, int n) {
    int idx = blockIdx.x * 1024 + threadIdx.x * 4;
    int s = 0;
#pragma unroll
    for (int r = 0; r < 4; ++r)
        if (idx + r < n) s += deg16[(idx + r) << 4];
#pragma unroll
    for (int m = 1; m < 64; m <<= 1) s += __shfl_xor(s, m);
    __shared__ int ws[4];
    if ((threadIdx.x & 63) == 0) ws[threadIdx.x >> 6] = s;
    __syncthreads();
    if (threadIdx.x == 0) bsum[blockIdx.x] = ws[0] + ws[1] + ws[2] + ws[3];
}

__global__ __launch_bounds__(256) void k_scan_tops(int* __restrict__ bsum, int B) {
    __shared__ int lds[256];
    int t = threadIdx.x;
    int v = (t < B) ? bsum[t] : 0;
    lds[t] = v;
    __syncthreads();
    int acc = v;
    for (int ofs = 1; ofs < 256; ofs <<= 1) {
        int u = (t >= ofs) ? lds[t - ofs] : 0;
        __syncthreads();
        acc += u;
        lds[t] = acc;
        __syncthreads();
    }
    if (t < B) bsum[t] = acc - v;  // exclusive block offsets (in place)
}

__global__ __launch_bounds__(256) void k_scan_add(const int* __restrict__ deg16,
                                                  const int* __restrict__ bsum,
                                                  int* __restrict__ row_start,
                                                  int* __restrict__ cursor16, int n, int total) {
    int t = threadIdx.x;
    int idx = blockIdx.x * 1024 + t * 4;
    int v[4] = {0, 0, 0, 0};
#pragma unroll
    for (int r = 0; r < 4; ++r)
        if (idx + r < n) v[r] = deg16[(idx + r) << 4];
    int s = v[0] + v[1] + v[2] + v[3];
    __shared__ int lds[256];
    lds[t] = s;
    __syncthreads();
    int acc = s;
    for (int ofs = 1; ofs < 256; ofs <<= 1) {
        int u = (t >= ofs) ? lds[t - ofs] : 0;
        __syncthreads();
        acc += u;
        lds[t] = acc;
        __syncthreads();
    }
    int excl = bsum[blockIdx.x] + acc - s;
    int rs[4];
    rs[0] = excl;
    rs[1] = rs[0] + v[0];
    rs[2] = rs[1] + v[1];
    rs[3] = rs[2] + v[2];
    if (idx + 3 < n) {
        *(int4*)(row_start + idx) = make_int4(rs[0], rs[1], rs[2], rs[3]);
    } else {
#pragma unroll
        for (int r = 0; r < 4; ++r)
            if (idx + r < n) row_start[idx + r] = rs[r];
    }
#pragma unroll
    for (int r = 0; r < 4; ++r)
        if (idx + r < n) cursor16[(idx + r) << 4] = rs[r];
    if (blockIdx.x == 0 && t == 0) row_start[n] = total;
}

// ---------------- K5: scatter edges (and self loops) into CSR ----------------
__global__ void k_scatter(const int* __restrict__ src, const int* __restrict__ dst,
                          int* __restrict__ cursor16, int* __restrict__ csr, int E, int n) {
    int t = blockIdx.x * blockDim.x + threadIdx.x;
    if (t < E) {
        int d = dst[t];
        int slot = atomicAdd(&cursor16[d << 4], 1);
        csr[slot] = src[t];
    } else if (t < E + n) {
        int i = t - E;
        int slot = atomicAdd(&cursor16[i << 4], 1);
        csr[slot] = i;
    }
}

// ---------------- K6: per-dst-node single-pass max-free softmax aggregation,
//                      16-edge clamp-masked batches (32 gathers in flight).
//                      Lane l: channels {c, c+16}, c = 32*(l>>4)+(l&15); head l>>4.
__global__ __launch_bounds__(256) void k_agg(const unsigned int* __restrict__ hw,
                                             const float* __restrict__ asrc,
                                             const float* __restrict__ adst,
                                             const int* __restrict__ row_start,
                                             const int* __restrict__ csr,
                                             const float* __restrict__ prev,
                                             const float* __restrict__ bias,
                                             float* __restrict__ ypre,
                                             float* __restrict__ stats, int n) {
    const int lane = threadIdx.x & 63;
    const int hd = lane >> 4;                 // head
    const int ch = 32 * hd + (lane & 15);     // channel pair {ch, ch+16}
    int wave = blockIdx.x * 4 + (threadIdx.x >> 6);
    int nw = gridDim.x * 4;
    const float bb0 = bias[ch], bb1 = bias[ch + 16];
    float bsum0 = 0.f, bsq0 = 0.f, bsum1 = 0.f, bsq1 = 0.f;
    for (int i0 = wave; i0 < n; i0 += nw) {
        int i = __builtin_amdgcn_readfirstlane(i0);
        int e0 = row_start[i], e1 = row_start[i + 1];
        const float adx = adst[i * 4 + hd];
        float s = 0.f, acc0 = 0.f, acc1 = 0.f;
        for (int e = e0; e < e1; e += 16) {
            int j[16];
            float g[16];
            unsigned int hp[16];
#pragma unroll
            for (int r = 0; r < 16; ++r) j[r] = csr[min(e + r, e1 - 1)];
#pragma unroll
            for (int r = 0; r < 16; ++r) g[r] = asrc[j[r] * 4 + hd];
#pragma unroll
            for (int r = 0; r < 16; ++r) hp[r] = hw[(size_t)j[r] * 64 + lane];
#pragma unroll
            for (int r = 0; r < 16; ++r) {
                float p = (e + r < e1) ? EXP2(leaky(g[r] + adx)) : 0.f;
                s += p;
                acc0 = fmaf(p, __uint_as_float(hp[r] << 16), acc0);
                acc1 = fmaf(p, __uint_as_float(hp[r] & 0xffff0000u), acc1);
            }
        }
        float rs = 1.0f / s;
        size_t base = (size_t)i * DIM;
        float o0 = fmaf(acc0, rs, bb0 + prev[base + ch]);
        float o1 = fmaf(acc1, rs, bb1 + prev[base + ch + 16]);
        ypre[base + ch] = o0;
        ypre[base + ch + 16] = o1;
        bsum0 += o0; bsq0 = fmaf(o0, o0, bsq0);
        bsum1 += o1; bsq1 = fmaf(o1, o1, bsq1);
    }
    __shared__ float red[4][256];
    red[0][threadIdx.x] = bsum0;
    red[1][threadIdx.x] = bsq0;
    red[2][threadIdx.x] = bsum1;
    red[3][threadIdx.x] = bsq1;
    __syncthreads();
    if (threadIdx.x < 64) {
        int t = threadIdx.x;
        int c = 32 * (t >> 4) + (t & 15);
        float v0 = red[0][t] + red[0][t + 64] + red[0][t + 128] + red[0][t + 192];
        float v1 = red[1][t] + red[1][t + 64] + red[1][t + 128] + red[1][t + 192];
        float v2 = red[2][t] + red[2][t + 64] + red[2][t + 128] + red[2][t + 192];
        float v3 = red[3][t] + red[3][t + 64] + red[3][t + 128] + red[3][t + 192];
        atomicAdd(&stats[c], v0);             // sum, channel c
        atomicAdd(&stats[c + 16], v2);        // sum, channel c+16
        atomicAdd(&stats[128 + c], v1);       // sumsq, channel c
        atomicAdd(&stats[128 + c + 16], v3);  // sumsq, channel c+16
    }
}

// ---------------- K7: finalize BN scale/shift ----------------
__global__ void k_bnfin(const float* __restrict__ stats, const float* __restrict__ gamma,
                        const float* __restrict__ beta, float* __restrict__ AB, int n) {
    int c = threadIdx.x;  // 128 threads
    float fn = (float)n;
    float mean = stats[c] / fn;
    float var = stats[128 + c] / fn - mean * mean;
    float a = gamma[c] * rsqrtf(var + EPS);
    AB[c] = a;
    AB[128 + c] = beta[c] - mean * a;
}

// ---------------- K8: y = relu(y*A + B), in place, float4 ----------------
__global__ __launch_bounds__(256) void k_final(float* __restrict__ y,
                                               const float* __restrict__ AB, int total4) {
    int t0 = blockIdx.x * blockDim.x + threadIdx.x;
    int stride = gridDim.x * blockDim.x;
    for (int t = t0; t < total4; t += stride) {
        float4 v = ((float4*)y)[t];
        int c0 = (t * 4) & 127;
        v.x = fmaf(v.x, AB[c0 + 0], AB[128 + c0 + 0]);
        v.y = fmaf(v.y, AB[c0 + 1], AB[128 + c0 + 1]);
        v.z = fmaf(v.z, AB[c0 + 2], AB[128 + c0 + 2]);
        v.w = fmaf(v.w, AB[c0 + 3], AB[128 + c0 + 3]);
        v.x = v.x > 0.f ? v.x : 0.f;
        v.y = v.y > 0.f ? v.y : 0.f;
        v.z = v.z > 0.f ? v.z : 0.f;
        v.w = v.w > 0.f ? v.w : 0.f;
        ((float4*)y)[t] = v;
    }
}

extern "C" void kernel_launch(void* const* d_in, const int* in_sizes, int n_in,
                              void* d_out, int out_size, void* d_ws, size_t ws_size,
                              hipStream_t stream) {
    const float* prev  = (const float*)d_in[0];
    const float* x     = (const float*)d_in[1];
    const int*   ei    = (const int*)d_in[2];
    const float* W     = (const float*)d_in[3];
    const float* att_s = (const float*)d_in[4];
    const float* att_d = (const float*)d_in[5];
    const float* bias  = (const float*)d_in[6];
    const float* gamma = (const float*)d_in[7];
    const float* beta  = (const float*)d_in[8];
    const int n = in_sizes[0] / DIM;
    const int E = in_sizes[2] / 2;
    const int* src = ei;
    const int* dst = ei + E;

    char* p = (char*)d_ws;
    auto alloc = [&](size_t bytes) {
        void* q = (void*)p;
        p += (bytes + 255) & ~(size_t)255;
        return q;
    };
    unsigned int* hpk = (unsigned int*)alloc((size_t)n * 64 * 4);
    float* asrc      = (float*)alloc((size_t)n * 4 * 4);
    float* adst      = (float*)alloc((size_t)n * 4 * 4);
    int*   deg16     = (int*)alloc((size_t)n * 16 * 4);     // 1 counter / 64B line
    int*   row_start = (int*)alloc((size_t)(n + 1) * 4);
    int*   cursor16  = (int*)alloc((size_t)n * 16 * 4);     // 1 cursor / 64B line
    int*   csr       = (int*)alloc((size_t)(E + n) * 4);
    int*   bsum      = (int*)alloc(1024 * 4);
    float* stats     = (float*)alloc(256 * 4);
    float* AB        = (float*)alloc(256 * 4);
    float* yout      = (float*)d_out;

    int B = (n + 1023) / 1024;  // scan blocks (<=256 for n<=262144)
    k_init<<<dim3((n + 255) / 256), dim3(256), 0, stream>>>(deg16, stats, n);
    k_gemm<<<dim3(2048), dim3(256), 0, stream>>>(x, W, att_s, att_d, hpk, asrc, adst, n);
    k_hist<<<dim3((E + 255) / 256), dim3(256), 0, stream>>>(dst, deg16, E);
    k_scan_part<<<dim3(B), dim3(256), 0, stream>>>(deg16, bsum, n);
    k_scan_tops<<<dim3(1), dim3(256), 0, stream>>>(bsum, B);
    k_scan_add<<<dim3(B), dim3(256), 0, stream>>>(deg16, bsum, row_start, cursor16, n, E + n);
    k_scatter<<<dim3((E + n + 255) / 256), dim3(256), 0, stream>>>(src, dst, cursor16, csr, E, n);
    k_agg<<<dim3(2048), dim3(256), 0, stream>>>(hpk, asrc, adst, row_start, csr, prev, bias, yout, stats, n);
    k_bnfin<<<dim3(1), dim3(128), 0, stream>>>(stats, gamma, beta, AB, n);
    int total4 = n * DIM / 4;
    k_final<<<dim3(2048), dim3(256), 0, stream>>>(yout, AB, total4);
}

// Round 11
// 301.614 us; speedup vs baseline: 1.7820x; 1.2361x over previous
//
#include <hip/hip_runtime.h>
#include <math.h>

#define DIM 128
#define NEG 0.2f
#define EPS 1e-5f
#define LOG2E 1.4426950408889634f

#if __has_builtin(__builtin_amdgcn_exp2f)
#define EXP2(x) __builtin_amdgcn_exp2f(x)
#else
#define EXP2(x) exp2f(x)
#endif

typedef __attribute__((ext_vector_type(8))) short short8v;  // bf16x8 MFMA frag
typedef __attribute__((ext_vector_type(4))) float f32x4;

static __device__ __forceinline__ float leaky(float a) { return a > 0.f ? a : NEG * a; }
static __device__ __forceinline__ unsigned short f2bf(float f) {
    unsigned int u = __float_as_uint(f);
    unsigned int r = (u + 0x7fffu + ((u >> 16) & 1u)) >> 16;  // RNE
    return (unsigned short)r;
}

// ---------------- K1: h = x@W via MFMA bf16. Block=256 (4 waves).
// Wave w owns head w = cols [32w, 32w+32). B-frags (W) live in registers for
// the whole kernel. Per chunk: 16 rows staged as bf16 in LDS, 8 MFMAs/wave.
// hpk word l of row r = channels {c, c+16}, c = 32*(l>>4) + (l&15).
__global__ __launch_bounds__(256) void k_gemm(const float* __restrict__ x,
                                              const float* __restrict__ W,
                                              const float* __restrict__ att_s,
                                              const float* __restrict__ att_d,
                                              unsigned int* __restrict__ hpk,
                                              float* __restrict__ asrc,
                                              float* __restrict__ adst, int n) {
    __shared__ __align__(16) unsigned short xs[16][136];  // 16 rows bf16, padded
    const int tid = threadIdx.x;
    const int w = tid >> 6;    // wave = head
    const int lane = tid & 63;
    const int lm = lane & 15;  // m (A row) / n (B col) index
    const int lk = lane >> 4;  // k-group
    short8v bfrag[2][4];
#pragma unroll
    for (int ct = 0; ct < 2; ++ct) {
        int c = w * 32 + ct * 16 + lm;
#pragma unroll
        for (int q = 0; q < 4; ++q) {
            short8v f;
#pragma unroll
            for (int j = 0; j < 8; ++j) {
                int k = q * 32 + lk * 8 + j;
                f[j] = (short)f2bf(W[k * DIM + c]);
            }
            bfrag[ct][q] = f;
        }
    }
    const float asv0 = att_s[w * 32 + lm] * LOG2E;
    const float asv1 = att_s[w * 32 + 16 + lm] * LOG2E;
    const float adv0 = att_d[w * 32 + lm] * LOG2E;
    const float adv1 = att_d[w * 32 + 16 + lm] * LOG2E;

    const int nchunk = (n + 15) >> 4;
    for (int chunk = blockIdx.x; chunk < nchunk; chunk += gridDim.x) {
        const int r0 = chunk * 16;
        {   // stage 16 rows of x -> bf16 LDS (coalesced 32B/thread)
            int row = tid >> 4;
            int c8 = (tid & 15) * 8;
            int rg = min(r0 + row, n - 1);
            const float4* xp = (const float4*)(x + (size_t)rg * DIM + c8);
            float4 v0 = xp[0], v1 = xp[1];
            short8v t;
            t[0] = (short)f2bf(v0.x); t[1] = (short)f2bf(v0.y);
            t[2] = (short)f2bf(v0.z); t[3] = (short)f2bf(v0.w);
            t[4] = (short)f2bf(v1.x); t[5] = (short)f2bf(v1.y);
            t[6] = (short)f2bf(v1.z); t[7] = (short)f2bf(v1.w);
            *(short8v*)(&xs[row][c8]) = t;
        }
        __syncthreads();
        f32x4 acc0 = {0.f, 0.f, 0.f, 0.f}, acc1 = {0.f, 0.f, 0.f, 0.f};
#pragma unroll
        for (int q = 0; q < 4; ++q) {
            short8v a = *(const short8v*)(&xs[lm][q * 32 + lk * 8]);
            acc0 = __builtin_amdgcn_mfma_f32_16x16x32_bf16(a, bfrag[0][q], acc0, 0, 0, 0);
            acc1 = __builtin_amdgcn_mfma_f32_16x16x32_bf16(a, bfrag[1][q], acc1, 0, 0, 0);
        }
        __syncthreads();  // xs consumed; safe to restage next chunk
        float ps[4], qs[4];
#pragma unroll
        for (int j = 0; j < 4; ++j) {
            ps[j] = acc0[j] * asv0 + acc1[j] * asv1;
            qs[j] = acc0[j] * adv0 + acc1[j] * adv1;
        }
#pragma unroll
        for (int m = 1; m < 16; m <<= 1) {
#pragma unroll
            for (int j = 0; j < 4; ++j) {
                ps[j] += __shfl_xor(ps[j], m);
                qs[j] += __shfl_xor(qs[j], m);
            }
        }
#pragma unroll
        for (int j = 0; j < 4; ++j) {
            int r = r0 + 4 * lk + j;
            if (r < n) {
                hpk[(size_t)r * 64 + 16 * w + lm] =
                    (unsigned int)f2bf(acc0[j]) | ((unsigned int)f2bf(acc1[j]) << 16);
                if (lm == 0) {
                    asrc[r * 4 + w] = ps[j];
                    adst[r * 4 + w] = qs[j];
                }
            }
        }
    }
}

// ---------------- K2: init deg16=1 (self loop, line-padded) + zero BN stats --
__global__ void k_init(int* __restrict__ deg16, float* __restrict__ stats, int n) {
    int t = blockIdx.x * blockDim.x + threadIdx.x;
    if (t < n) deg16[t << 4] = 1;
    if (t < 256) stats[t] = 0.f;
}

// ---------------- K3: histogram of dst (one counter per 64B line) ----------
__global__ void k_hist(const int* __restrict__ dst, int* __restrict__ deg16, int E) {
    int t = blockIdx.x * blockDim.x + threadIdx.x;
    if (t < E) atomicAdd(&deg16[dst[t] << 4], 1);
}

// ---------------- K4abc: device-wide exclusive scan of deg16 (1024/block) ----
__global__ __launch_bounds__(256) void k_scan_part(const int* __restrict__ deg16,
                                                   int* __restrict__ bsum, int n) {
    int idx = blockIdx.x * 1024 + threadIdx.x * 4;
    int s = 0;
#pragma unroll
    for (int r = 0; r < 4; ++r)
        if (idx + r < n) s += deg16[(idx + r) << 4];
#pragma unroll
    for (int m = 1; m < 64; m <<= 1) s += __shfl_xor(s, m);
    __shared__ int ws[4];
    if ((threadIdx.x & 63) == 0) ws[threadIdx.x >> 6] = s;
    __syncthreads();
    if (threadIdx.x == 0) bsum[blockIdx.x] = ws[0] + ws[1] + ws[2] + ws[3];
}

__global__ __launch_bounds__(256) void k_scan_tops(int* __restrict__ bsum, int B) {
    __shared__ int lds[256];
    int t = threadIdx.x;
    int v = (t < B) ? bsum[t] : 0;
    lds[t] = v;
    __syncthreads();
    int acc = v;
    for (int ofs = 1; ofs < 256; ofs <<= 1) {
        int u = (t >= ofs) ? lds[t - ofs] : 0;
        __syncthreads();
        acc += u;
        lds[t] = acc;
        __syncthreads();
    }
    if (t < B) bsum[t] = acc - v;  // exclusive block offsets (in place)
}

__global__ __launch_bounds__(256) void k_scan_add(const int* __restrict__ deg16,
                                                  const int* __restrict__ bsum,
                                                  int* __restrict__ row_start,
                                                  int* __restrict__ cursor16, int n, int total) {
    int t = threadIdx.x;
    int idx = blockIdx.x * 1024 + t * 4;
    int v[4] = {0, 0, 0, 0};
#pragma unroll
    for (int r = 0; r < 4; ++r)
        if (idx + r < n) v[r] = deg16[(idx + r) << 4];
    int s = v[0] + v[1] + v[2] + v[3];
    __shared__ int lds[256];
    lds[t] = s;
    __syncthreads();
    int acc = s;
    for (int ofs = 1; ofs < 256; ofs <<= 1) {
        int u = (t >= ofs) ? lds[t - ofs] : 0;
        __syncthreads();
        acc += u;
        lds[t] = acc;
        __syncthreads();
    }
    int excl = bsum[blockIdx.x] + acc - s;
    int rs[4];
    rs[0] = excl;
    rs[1] = rs[0] + v[0];
    rs[2] = rs[1] + v[1];
    rs[3] = rs[2] + v[2];
    if (idx + 3 < n) {
        *(int4*)(row_start + idx) = make_int4(rs[0], rs[1], rs[2], rs[3]);
    } else {
#pragma unroll
        for (int r = 0; r < 4; ++r)
            if (idx + r < n) row_start[idx + r] = rs[r];
    }
#pragma unroll
    for (int r = 0; r < 4; ++r)
        if (idx + r < n) cursor16[(idx + r) << 4] = rs[r];
    if (blockIdx.x == 0 && t == 0) row_start[n] = total;
}

// ---------------- K5: XCD-affine windowed scatter.
// Block-group g = blockIdx&7 (maps round-robin to one XCD) owns node window
// [g*wsz, (g+1)*wsz). Each group scans the FULL edge list (dense reads,
// MALL-resident) and scatters only its window's edges -> csr/cursor lines are
// written by ONE XCD only: stores merge in its L2, write back as dense lines.
__global__ __launch_bounds__(256) void k_scatter(const int* __restrict__ src,
                                                 const int* __restrict__ dst,
                                                 int* __restrict__ cursor16,
                                                 int* __restrict__ csr,
                                                 int E, int n) {
    const int g = blockIdx.x & 7;
    const int gb = blockIdx.x >> 3;
    const int nblk = gridDim.x >> 3;
    const int wsz = (n + 7) >> 3;
    const int lo = g * wsz;
    const int hi = min(lo + wsz, n);
    const int total = E + n;
    const int step = nblk * 256;
    for (int t = gb * 256 + threadIdx.x; t < total; t += step) {
        int d, sv;
        if (t < E) {
            d = dst[t];
            sv = src[t];
        } else {
            d = t - E;
            sv = d;
        }
        if (d >= lo && d < hi) {
            int slot = atomicAdd(&cursor16[d << 4], 1);
            csr[slot] = sv;
        }
    }
}

// ---------------- K6: per-dst-node single-pass max-free softmax aggregation,
//                      16-edge clamp-masked batches (32 gathers in flight).
//                      Lane l: channels {c, c+16}, c = 32*(l>>4)+(l&15); head l>>4.
__global__ __launch_bounds__(256) void k_agg(const unsigned int* __restrict__ hw,
                                             const float* __restrict__ asrc,
                                             const float* __restrict__ adst,
                                             const int* __restrict__ row_start,
                                             const int* __restrict__ csr,
                                             const float* __restrict__ prev,
                                             const float* __restrict__ bias,
                                             float* __restrict__ ypre,
                                             float* __restrict__ stats, int n) {
    const int lane = threadIdx.x & 63;
    const int hd = lane >> 4;                 // head
    const int ch = 32 * hd + (lane & 15);     // channel pair {ch, ch+16}
    int wave = blockIdx.x * 4 + (threadIdx.x >> 6);
    int nw = gridDim.x * 4;
    const float bb0 = bias[ch], bb1 = bias[ch + 16];
    float bsum0 = 0.f, bsq0 = 0.f, bsum1 = 0.f, bsq1 = 0.f;
    for (int i0 = wave; i0 < n; i0 += nw) {
        int i = __builtin_amdgcn_readfirstlane(i0);
        int e0 = row_start[i], e1 = row_start[i + 1];
        const float adx = adst[i * 4 + hd];
        float s = 0.f, acc0 = 0.f, acc1 = 0.f;
        for (int e = e0; e < e1; e += 16) {
            int j[16];
            float g[16];
            unsigned int hp[16];
#pragma unroll
            for (int r = 0; r < 16; ++r) j[r] = csr[min(e + r, e1 - 1)];
#pragma unroll
            for (int r = 0; r < 16; ++r) g[r] = asrc[j[r] * 4 + hd];
#pragma unroll
            for (int r = 0; r < 16; ++r) hp[r] = hw[(size_t)j[r] * 64 + lane];
#pragma unroll
            for (int r = 0; r < 16; ++r) {
                float p = (e + r < e1) ? EXP2(leaky(g[r] + adx)) : 0.f;
                s += p;
                acc0 = fmaf(p, __uint_as_float(hp[r] << 16), acc0);
                acc1 = fmaf(p, __uint_as_float(hp[r] & 0xffff0000u), acc1);
            }
        }
        float rs = 1.0f / s;
        size_t base = (size_t)i * DIM;
        float o0 = fmaf(acc0, rs, bb0 + prev[base + ch]);
        float o1 = fmaf(acc1, rs, bb1 + prev[base + ch + 16]);
        ypre[base + ch] = o0;
        ypre[base + ch + 16] = o1;
        bsum0 += o0; bsq0 = fmaf(o0, o0, bsq0);
        bsum1 += o1; bsq1 = fmaf(o1, o1, bsq1);
    }
    __shared__ float red[4][256];
    red[0][threadIdx.x] = bsum0;
    red[1][threadIdx.x] = bsq0;
    red[2][threadIdx.x] = bsum1;
    red[3][threadIdx.x] = bsq1;
    __syncthreads();
    if (threadIdx.x < 64) {
        int t = threadIdx.x;
        int c = 32 * (t >> 4) + (t & 15);
        float v0 = red[0][t] + red[0][t + 64] + red[0][t + 128] + red[0][t + 192];
        float v1 = red[1][t] + red[1][t + 64] + red[1][t + 128] + red[1][t + 192];
        float v2 = red[2][t] + red[2][t + 64] + red[2][t + 128] + red[2][t + 192];
        float v3 = red[3][t] + red[3][t + 64] + red[3][t + 128] + red[3][t + 192];
        atomicAdd(&stats[c], v0);             // sum, channel c
        atomicAdd(&stats[c + 16], v2);        // sum, channel c+16
        atomicAdd(&stats[128 + c], v1);       // sumsq, channel c
        atomicAdd(&stats[128 + c + 16], v3);  // sumsq, channel c+16
    }
}

// ---------------- K7: finalize BN scale/shift ----------------
__global__ void k_bnfin(const float* __restrict__ stats, const float* __restrict__ gamma,
                        const float* __restrict__ beta, float* __restrict__ AB, int n) {
    int c = threadIdx.x;  // 128 threads
    float fn = (float)n;
    float mean = stats[c] / fn;
    float var = stats[128 + c] / fn - mean * mean;
    float a = gamma[c] * rsqrtf(var + EPS);
    AB[c] = a;
    AB[128 + c] = beta[c] - mean * a;
}

// ---------------- K8: y = relu(y*A + B), in place, float4 ----------------
__global__ __launch_bounds__(256) void k_final(float* __restrict__ y,
                                               const float* __restrict__ AB, int total4) {
    int t0 = blockIdx.x * blockDim.x + threadIdx.x;
    int stride = gridDim.x * blockDim.x;
    for (int t = t0; t < total4; t += stride) {
        float4 v = ((float4*)y)[t];
        int c0 = (t * 4) & 127;
        v.x = fmaf(v.x, AB[c0 + 0], AB[128 + c0 + 0]);
        v.y = fmaf(v.y, AB[c0 + 1], AB[128 + c0 + 1]);
        v.z = fmaf(v.z, AB[c0 + 2], AB[128 + c0 + 2]);
        v.w = fmaf(v.w, AB[c0 + 3], AB[128 + c0 + 3]);
        v.x = v.x > 0.f ? v.x : 0.f;
        v.y = v.y > 0.f ? v.y : 0.f;
        v.z = v.z > 0.f ? v.z : 0.f;
        v.w = v.w > 0.f ? v.w : 0.f;
        ((float4*)y)[t] = v;
    }
}

extern "C" void kernel_launch(void* const* d_in, const int* in_sizes, int n_in,
                              void* d_out, int out_size, void* d_ws, size_t ws_size,
                              hipStream_t stream) {
    const float* prev  = (const float*)d_in[0];
    const float* x     = (const float*)d_in[1];
    const int*   ei    = (const int*)d_in[2];
    const float* W     = (const float*)d_in[3];
    const float* att_s = (const float*)d_in[4];
    const float* att_d = (const float*)d_in[5];
    const float* bias  = (const float*)d_in[6];
    const float* gamma = (const float*)d_in[7];
    const float* beta  = (const float*)d_in[8];
    const int n = in_sizes[0] / DIM;
    const int E = in_sizes[2] / 2;
    const int* src = ei;
    const int* dst = ei + E;

    char* p = (char*)d_ws;
    auto alloc = [&](size_t bytes) {
        void* q = (void*)p;
        p += (bytes + 255) & ~(size_t)255;
        return q;
    };
    unsigned int* hpk = (unsigned int*)alloc((size_t)n * 64 * 4);
    float* asrc      = (float*)alloc((size_t)n * 4 * 4);
    float* adst      = (float*)alloc((size_t)n * 4 * 4);
    int*   deg16     = (int*)alloc((size_t)n * 16 * 4);     // 1 counter / 64B line
    int*   row_start = (int*)alloc((size_t)(n + 1) * 4);
    int*   cursor16  = (int*)alloc((size_t)n * 16 * 4);     // 1 cursor / 64B line
    int*   csr       = (int*)alloc((size_t)(E + n) * 4);
    int*   bsum      = (int*)alloc(1024 * 4);
    float* stats     = (float*)alloc(256 * 4);
    float* AB        = (float*)alloc(256 * 4);
    float* yout      = (float*)d_out;

    int B = (n + 1023) / 1024;  // scan blocks (<=256 for n<=262144)
    k_init<<<dim3((n + 255) / 256), dim3(256), 0, stream>>>(deg16, stats, n);
    k_gemm<<<dim3(2048), dim3(256), 0, stream>>>(x, W, att_s, att_d, hpk, asrc, adst, n);
    k_hist<<<dim3((E + 255) / 256), dim3(256), 0, stream>>>(dst, deg16, E);
    k_scan_part<<<dim3(B), dim3(256), 0, stream>>>(deg16, bsum, n);
    k_scan_tops<<<dim3(1), dim3(256), 0, stream>>>(bsum, B);
    k_scan_add<<<dim3(B), dim3(256), 0, stream>>>(deg16, bsum, row_start, cursor16, n, E + n);
    k_scatter<<<dim3(2048), dim3(256), 0, stream>>>(src, dst, cursor16, csr, E, n);
    k_agg<<<dim3(2048), dim3(256), 0, stream>>>(hpk, asrc, adst, row_start, csr, prev, bias, yout, stats, n);
    k_bnfin<<<dim3(1), dim3(128), 0, stream>>>(stats, gamma, beta, AB, n);
    int total4 = n * DIM / 4;
    k_final<<<dim3(2048), dim3(256), 0, stream>>>(yout, AB, total4);
}